// Round 1
// baseline (416.467 us; speedup 1.0000x reference)
//
#include <hip/hip_runtime.h>
#include <hip/hip_bf16.h>

#define BB 2
#define HH 16
#define SLEN 2048
#define DD 64
#define QB 64
#define KB 64

typedef __attribute__((ext_vector_type(8))) short bf16x8;
typedef __attribute__((ext_vector_type(4))) float f32x4;

__device__ __forceinline__ unsigned short f2bf(float x) {
  union { float f; unsigned u; } v; v.f = x;
  unsigned r = v.u + 0x7fffu + ((v.u >> 16) & 1u);
  return (unsigned short)(r >> 16);
}
__device__ __forceinline__ float bf2f(unsigned short h) {
  union { float f; unsigned u; } v; v.u = ((unsigned)h) << 16;
  return v.f;
}
// ushort-index into a [rows][64] LDS tile, XOR-swizzled to spread banks.
// XOR acts on bits 3..5 of the column (16B granule) -> ds_read_b128 stays
// contiguous+aligned; rows 8 apart share a pattern (2-way, free per m136).
__device__ __forceinline__ int swz(int row, int col) {
  return row * 64 + (col ^ ((row & 7) << 3));
}

__global__ __launch_bounds__(256) void attn_fwd(
    const float* __restrict__ q, const float* __restrict__ k,
    const float* __restrict__ v, const int* __restrict__ mask,
    float* __restrict__ out) {
  __shared__ unsigned short Khi[KB * DD];   // [t][d] hi bf16
  __shared__ unsigned short Klo[KB * DD];   // [t][d] lo bf16
  __shared__ unsigned short VT[DD * KB];    // [d][t] bf16
  __shared__ unsigned short Pl[4][16 * KB]; // per-wave P tile [qrow][t]

  const int tid = threadIdx.x;
  const int w = tid >> 6;        // wave 0..3
  const int l = tid & 63;        // lane
  const int lg = l >> 4;         // lane group 0..3
  const int ln = l & 15;

  const int qt = blockIdx.x;     // query tile 0..31
  const int bh = blockIdx.y;     // 0..31
  const int b = bh / HH;

  const float* qbase = q + ((size_t)bh * SLEN + (size_t)qt * QB) * DD;
  const float* kbase = k + (size_t)bh * DD * SLEN;   // key is [D][S]
  const float* vbase = v + (size_t)bh * SLEN * DD;
  float* obase = out + ((size_t)bh * SLEN + (size_t)qt * QB) * DD;

  // ---- Q fragments in registers (hi/lo split), rows w*16+ln ----
  bf16x8 qhi[2], qlo[2];
  {
    const float* qrow = qbase + (size_t)(w * 16 + ln) * DD;
#pragma unroll
    for (int c = 0; c < 2; ++c) {
      int d0 = c * 32 + lg * 8;
#pragma unroll
      for (int j = 0; j < 8; ++j) {
        float x = qrow[d0 + j];
        unsigned short hi = f2bf(x);
        qhi[c][j] = (short)hi;
        qlo[c][j] = (short)f2bf(x - bf2f(hi));
      }
    }
  }

  // ---- per-output-row mask additive (row = lg*4 + r within wave tile) ----
  float addv[4];
#pragma unroll
  for (int r = 0; r < 4; ++r) {
    int grow = qt * QB + w * 16 + lg * 4 + r;
    addv[r] = mask[b * SLEN + grow] ? 0.0f : -1e12f;
  }

  f32x4 oacc[4];
#pragma unroll
  for (int nt = 0; nt < 4; ++nt) oacc[nt] = (f32x4){0.f, 0.f, 0.f, 0.f};
  float mrun[4], lrun[4];
#pragma unroll
  for (int r = 0; r < 4; ++r) { mrun[r] = -INFINITY; lrun[r] = 0.f; }

  for (int kt = 0; kt < SLEN / KB; ++kt) {
    const int t0 = kt * KB;
    __syncthreads();  // prior tile's LDS reads done before overwrite
    // ---- stage K tile: global [d][t] -> LDS [t][d], hi/lo bf16 ----
#pragma unroll
    for (int i = 0; i < 4; ++i) {
      int f4 = tid + 256 * i;        // 1024 float4s
      int d = f4 >> 4;               // 0..63
      int c4 = f4 & 15;              // 16 float4 per d-row
      const float4 kv = *reinterpret_cast<const float4*>(
          kbase + (size_t)d * SLEN + t0 + c4 * 4);
      float xs[4] = {kv.x, kv.y, kv.z, kv.w};
#pragma unroll
      for (int u = 0; u < 4; ++u) {
        int t = c4 * 4 + u;
        unsigned short hi = f2bf(xs[u]);
        Khi[swz(t, d)] = hi;
        Klo[swz(t, d)] = f2bf(xs[u] - bf2f(hi));
      }
    }
    // ---- stage V tile: global [t][d] -> LDS VT[d][t] bf16 ----
#pragma unroll
    for (int i = 0; i < 4; ++i) {
      int f4 = tid + 256 * i;
      int tl = f4 >> 4;              // 0..63 local t
      int c4 = f4 & 15;
      const float4 vv = *reinterpret_cast<const float4*>(
          vbase + (size_t)(t0 + tl) * DD + c4 * 4);
      float xs[4] = {vv.x, vv.y, vv.z, vv.w};
#pragma unroll
      for (int u = 0; u < 4; ++u) VT[swz(c4 * 4 + u, tl)] = f2bf(xs[u]);
    }
    __syncthreads();

    // ---- S = Q K^T (hi/lo split, 3 MFMAs per pair) ----
    f32x4 sacc[4];
#pragma unroll
    for (int nt = 0; nt < 4; ++nt) sacc[nt] = (f32x4){0.f, 0.f, 0.f, 0.f};
#pragma unroll
    for (int c = 0; c < 2; ++c) {
      int d0 = c * 32 + lg * 8;
#pragma unroll
      for (int nt = 0; nt < 4; ++nt) {
        int trow = nt * 16 + ln;
        bf16x8 bhf = *reinterpret_cast<bf16x8*>(&Khi[swz(trow, d0)]);
        bf16x8 blf = *reinterpret_cast<bf16x8*>(&Klo[swz(trow, d0)]);
        sacc[nt] = __builtin_amdgcn_mfma_f32_16x16x32_bf16(qhi[c], bhf, sacc[nt], 0, 0, 0);
        sacc[nt] = __builtin_amdgcn_mfma_f32_16x16x32_bf16(qlo[c], bhf, sacc[nt], 0, 0, 0);
        sacc[nt] = __builtin_amdgcn_mfma_f32_16x16x32_bf16(qhi[c], blf, sacc[nt], 0, 0, 0);
      }
    }

    // ---- online softmax (C/D layout: row=lg*4+r, col=nt*16+ln) ----
    float sv[4][4];
    float rm[4];
#pragma unroll
    for (int r = 0; r < 4; ++r) rm[r] = -INFINITY;
#pragma unroll
    for (int nt = 0; nt < 4; ++nt)
#pragma unroll
      for (int r = 0; r < 4; ++r) {
        float x = sacc[nt][r] * 0.125f + addv[r];  // scale=1/sqrt(64), then mask
        sv[nt][r] = x;
        rm[r] = fmaxf(rm[r], x);
      }
#pragma unroll
    for (int mm = 1; mm < 16; mm <<= 1)
#pragma unroll
      for (int r = 0; r < 4; ++r)
        rm[r] = fmaxf(rm[r], __shfl_xor(rm[r], mm, 64));
    float sf[4], mnew[4];
#pragma unroll
    for (int r = 0; r < 4; ++r) {
      mnew[r] = fmaxf(mrun[r], rm[r]);
      sf[r] = expf(mrun[r] - mnew[r]);
      mrun[r] = mnew[r];
    }
    float rs[4] = {0.f, 0.f, 0.f, 0.f};
#pragma unroll
    for (int nt = 0; nt < 4; ++nt)
#pragma unroll
      for (int r = 0; r < 4; ++r) {
        float p = expf(sv[nt][r] - mnew[r]);
        sv[nt][r] = p;
        rs[r] += p;
      }
#pragma unroll
    for (int mm = 1; mm < 16; mm <<= 1)
#pragma unroll
      for (int r = 0; r < 4; ++r)
        rs[r] += __shfl_xor(rs[r], mm, 64);
#pragma unroll
    for (int r = 0; r < 4; ++r) lrun[r] = lrun[r] * sf[r] + rs[r];
#pragma unroll
    for (int nt = 0; nt < 4; ++nt)
#pragma unroll
      for (int r = 0; r < 4; ++r) oacc[nt][r] *= sf[r];

    // ---- P -> LDS (wave-private), re-shape to A-fragment layout ----
#pragma unroll
    for (int nt = 0; nt < 4; ++nt)
#pragma unroll
      for (int r = 0; r < 4; ++r)
        Pl[w][swz(lg * 4 + r, nt * 16 + ln)] = f2bf(sv[nt][r]);
    __syncthreads();  // also orders wave-local P write->read

    // ---- O += P V ----
#pragma unroll
    for (int c = 0; c < 2; ++c) {
      int tc = c * 32 + lg * 8;
      bf16x8 pa = *reinterpret_cast<bf16x8*>(&Pl[w][swz(ln, tc)]);
#pragma unroll
      for (int nt = 0; nt < 4; ++nt) {
        bf16x8 vb = *reinterpret_cast<bf16x8*>(&VT[swz(nt * 16 + ln, tc)]);
        oacc[nt] = __builtin_amdgcn_mfma_f32_16x16x32_bf16(pa, vb, oacc[nt], 0, 0, 0);
      }
    }
  }

  // ---- epilogue: divide by row sum, store ----
#pragma unroll
  for (int nt = 0; nt < 4; ++nt)
#pragma unroll
    for (int r = 0; r < 4; ++r) {
      int lrow = lg * 4 + r;
      obase[(size_t)(w * 16 + lrow) * DD + nt * 16 + ln] =
          oacc[nt][r] / lrun[r];
    }
}

extern "C" void kernel_launch(void* const* d_in, const int* in_sizes, int n_in,
                              void* d_out, int out_size, void* d_ws, size_t ws_size,
                              hipStream_t stream) {
  const float* q = (const float*)d_in[0];
  const float* k = (const float*)d_in[1];
  const float* v = (const float*)d_in[2];
  const int* mask = (const int*)d_in[3];
  float* out = (float*)d_out;
  dim3 grid(SLEN / QB, BB * HH);
  attn_fwd<<<grid, dim3(256), 0, stream>>>(q, k, v, mask, out);
}

// Round 2
// 270.306 us; speedup vs baseline: 1.5407x; 1.5407x over previous
//
#include <hip/hip_runtime.h>
#include <hip/hip_bf16.h>

#define BB 2
#define HH 16
#define SLEN 2048
#define DD 64
#define QB 64
#define KB 64
#define LOG2E 1.44269504088896340736f

typedef __attribute__((ext_vector_type(8))) short bf16x8;
typedef __attribute__((ext_vector_type(4))) float f32x4;

__device__ __forceinline__ unsigned short f2bf_rne(float x) {
  union { float f; unsigned u; } v; v.f = x;
  unsigned r = v.u + 0x7fffu + ((v.u >> 16) & 1u);
  return (unsigned short)(r >> 16);
}
__device__ __forceinline__ float bf2f(unsigned short h) {
  union { float f; unsigned u; } v; v.u = ((unsigned)h) << 16;
  return v.f;
}
// ushort-index into a [rows][64] LDS tile, XOR-swizzled: col bits 3..5 ^= row
// bits 0..2. 8-ushort (16B) granules stay contiguous; 8 consecutive rows
// cover all 32 banks for b128 ops; read pattern aliases only 2-way (free).
__device__ __forceinline__ int swz(int row, int col) {
  return row * 64 + (col ^ ((row & 7) << 3));
}

__global__ __launch_bounds__(256) void attn_fwd(
    const float* __restrict__ q, const float* __restrict__ k,
    const float* __restrict__ v, const int* __restrict__ mask,
    float* __restrict__ out) {
  __shared__ unsigned short Khi[KB * DD];   // [t][d] hi bf16 (truncated)
  __shared__ unsigned short Klo[KB * DD];   // [t][d] lo bf16
  __shared__ unsigned short VT[DD * KB];    // [d][t] bf16
  __shared__ unsigned short Pl[4][16 * KB]; // per-wave P tile [qrow][t]

  const int tid = threadIdx.x;
  const int w = tid >> 6;        // wave 0..3
  const int l = tid & 63;        // lane
  const int lg = l >> 4;         // lane group 0..3
  const int ln = l & 15;

  const int qt = blockIdx.x;     // query tile 0..31
  const int bh = blockIdx.y;     // 0..31
  const int b = bh / HH;

  const float* qbase = q + ((size_t)bh * SLEN + (size_t)qt * QB) * DD;
  const float* kbase = k + (size_t)bh * DD * SLEN;   // key is [D][S]
  const float* vbase = v + (size_t)bh * SLEN * DD;
  float* obase = out + ((size_t)bh * SLEN + (size_t)qt * QB) * DD;

  // staging roles: K — lane owns key-index t, chunk of 16 d's per wave.
  //                V — lane owns d,          chunk of 16 t's per wave.
  const int st_t = tid & 63;
  const int st_d0 = (tid >> 6) * 16;
  const int sv_d = tid & 63;
  const int sv_t0 = (tid >> 6) * 16;

  // ---- Q fragments in registers (hi/lo split), rows w*16+ln ----
  bf16x8 qhi[2], qlo[2];
  {
    const float* qrow = qbase + (size_t)(w * 16 + ln) * DD;
#pragma unroll
    for (int c = 0; c < 2; ++c) {
      int d0 = c * 32 + lg * 8;
#pragma unroll
      for (int j = 0; j < 8; ++j) {
        float x = qrow[d0 + j];
        unsigned short hi = f2bf_rne(x);
        qhi[c][j] = (short)hi;
        qlo[c][j] = (short)f2bf_rne(x - bf2f(hi));
      }
    }
  }

  // ---- per-output-row mask additive, pre-scaled by log2(e) ----
  float addv[4];
#pragma unroll
  for (int r = 0; r < 4; ++r) {
    int grow = qt * QB + w * 16 + lg * 4 + r;
    addv[r] = mask[b * SLEN + grow] ? 0.0f : -1e12f * LOG2E;
  }
  const float SC = 0.125f * LOG2E;  // 1/sqrt(64) * log2(e)

  f32x4 oacc[4];
#pragma unroll
  for (int nt = 0; nt < 4; ++nt) oacc[nt] = (f32x4){0.f, 0.f, 0.f, 0.f};
  float mrun[4], lrun[4];
#pragma unroll
  for (int r = 0; r < 4; ++r) { mrun[r] = -INFINITY; lrun[r] = 0.f; }

  for (int kt = 0; kt < SLEN / KB; ++kt) {
    const int t0 = kt * KB;
    __syncthreads();  // prior tile's LDS reads done before overwrite

    // ---- stage K tile: column loads (coalesced across lanes), trunc hi/lo,
    //      2+2 swizzled ds_write_b128 ----
    bf16x8 khiv0, khiv1, klov0, klov1, vv0, vv1;
#pragma unroll
    for (int j = 0; j < 8; ++j) {
      float x = kbase[(size_t)(st_d0 + j) * SLEN + t0 + st_t];
      unsigned u = __float_as_uint(x);
      unsigned short hi = (unsigned short)(u >> 16);
      khiv0[j] = (short)hi;
      klov0[j] = (short)(unsigned short)(__float_as_uint(x - bf2f(hi)) >> 16);
    }
#pragma unroll
    for (int j = 0; j < 8; ++j) {
      float x = kbase[(size_t)(st_d0 + 8 + j) * SLEN + t0 + st_t];
      unsigned u = __float_as_uint(x);
      unsigned short hi = (unsigned short)(u >> 16);
      khiv1[j] = (short)hi;
      klov1[j] = (short)(unsigned short)(__float_as_uint(x - bf2f(hi)) >> 16);
    }
    // ---- stage V tile: column-of-VT loads (coalesced), RNE, 2 b128 ----
#pragma unroll
    for (int j = 0; j < 8; ++j)
      vv0[j] = (short)f2bf_rne(vbase[(size_t)(t0 + sv_t0 + j) * DD + sv_d]);
#pragma unroll
    for (int j = 0; j < 8; ++j)
      vv1[j] = (short)f2bf_rne(vbase[(size_t)(t0 + sv_t0 + 8 + j) * DD + sv_d]);

    *reinterpret_cast<bf16x8*>(&Khi[swz(st_t, st_d0)])     = khiv0;
    *reinterpret_cast<bf16x8*>(&Khi[swz(st_t, st_d0 + 8)]) = khiv1;
    *reinterpret_cast<bf16x8*>(&Klo[swz(st_t, st_d0)])     = klov0;
    *reinterpret_cast<bf16x8*>(&Klo[swz(st_t, st_d0 + 8)]) = klov1;
    *reinterpret_cast<bf16x8*>(&VT[swz(sv_d, sv_t0)])      = vv0;
    *reinterpret_cast<bf16x8*>(&VT[swz(sv_d, sv_t0 + 8)])  = vv1;
    __syncthreads();

    // ---- S = Q K^T (hi/lo split, 3 MFMAs per pair) ----
    f32x4 sacc[4];
#pragma unroll
    for (int nt = 0; nt < 4; ++nt) sacc[nt] = (f32x4){0.f, 0.f, 0.f, 0.f};
#pragma unroll
    for (int c = 0; c < 2; ++c) {
      int d0 = c * 32 + lg * 8;
#pragma unroll
      for (int nt = 0; nt < 4; ++nt) {
        int trow = nt * 16 + ln;
        bf16x8 bhf = *reinterpret_cast<bf16x8*>(&Khi[swz(trow, d0)]);
        bf16x8 blf = *reinterpret_cast<bf16x8*>(&Klo[swz(trow, d0)]);
        sacc[nt] = __builtin_amdgcn_mfma_f32_16x16x32_bf16(qhi[c], bhf, sacc[nt], 0, 0, 0);
        sacc[nt] = __builtin_amdgcn_mfma_f32_16x16x32_bf16(qlo[c], bhf, sacc[nt], 0, 0, 0);
        sacc[nt] = __builtin_amdgcn_mfma_f32_16x16x32_bf16(qhi[c], blf, sacc[nt], 0, 0, 0);
      }
    }

    // ---- online softmax in log2 domain (C/D: row=lg*4+r, col=nt*16+ln) ----
    float sv[4][4];
    float rm[4];
#pragma unroll
    for (int r = 0; r < 4; ++r) rm[r] = -INFINITY;
#pragma unroll
    for (int nt = 0; nt < 4; ++nt)
#pragma unroll
      for (int r = 0; r < 4; ++r) {
        float x = sacc[nt][r] * SC + addv[r];
        sv[nt][r] = x;
        rm[r] = fmaxf(rm[r], x);
      }
#pragma unroll
    for (int mm = 1; mm < 16; mm <<= 1)
#pragma unroll
      for (int r = 0; r < 4; ++r)
        rm[r] = fmaxf(rm[r], __shfl_xor(rm[r], mm, 64));
    float sf[4], mnew[4];
#pragma unroll
    for (int r = 0; r < 4; ++r) {
      mnew[r] = fmaxf(mrun[r], rm[r]);
      sf[r] = exp2f(mrun[r] - mnew[r]);
      mrun[r] = mnew[r];
    }
    float rs[4] = {0.f, 0.f, 0.f, 0.f};
#pragma unroll
    for (int nt = 0; nt < 4; ++nt)
#pragma unroll
      for (int r = 0; r < 4; ++r) {
        float p = exp2f(sv[nt][r] - mnew[r]);
        sv[nt][r] = p;
        rs[r] += p;
      }
#pragma unroll
    for (int mm = 1; mm < 16; mm <<= 1)
#pragma unroll
      for (int r = 0; r < 4; ++r)
        rs[r] += __shfl_xor(rs[r], mm, 64);
#pragma unroll
    for (int r = 0; r < 4; ++r) lrun[r] = lrun[r] * sf[r] + rs[r];
#pragma unroll
    for (int nt = 0; nt < 4; ++nt)
#pragma unroll
      for (int r = 0; r < 4; ++r) oacc[nt][r] *= sf[r];

    // ---- P -> LDS (wave-private; same-wave RAW ordered by lgkmcnt) ----
#pragma unroll
    for (int nt = 0; nt < 4; ++nt)
#pragma unroll
      for (int r = 0; r < 4; ++r)
        Pl[w][swz(lg * 4 + r, nt * 16 + ln)] = f2bf_rne(sv[nt][r]);

    // ---- O += P V ----
#pragma unroll
    for (int c = 0; c < 2; ++c) {
      int tc = c * 32 + lg * 8;
      bf16x8 pa = *reinterpret_cast<bf16x8*>(&Pl[w][swz(ln, tc)]);
#pragma unroll
      for (int nt = 0; nt < 4; ++nt) {
        bf16x8 vb = *reinterpret_cast<bf16x8*>(&VT[swz(nt * 16 + ln, tc)]);
        oacc[nt] = __builtin_amdgcn_mfma_f32_16x16x32_bf16(pa, vb, oacc[nt], 0, 0, 0);
      }
    }
  }

  // ---- epilogue: divide by row sum, store ----
#pragma unroll
  for (int nt = 0; nt < 4; ++nt)
#pragma unroll
    for (int r = 0; r < 4; ++r) {
      int lrow = lg * 4 + r;
      obase[(size_t)(w * 16 + lrow) * DD + nt * 16 + ln] =
          oacc[nt][r] / lrun[r];
    }
}

extern "C" void kernel_launch(void* const* d_in, const int* in_sizes, int n_in,
                              void* d_out, int out_size, void* d_ws, size_t ws_size,
                              hipStream_t stream) {
  const float* q = (const float*)d_in[0];
  const float* k = (const float*)d_in[1];
  const float* v = (const float*)d_in[2];
  const int* mask = (const int*)d_in[3];
  float* out = (float*)d_out;
  dim3 grid(SLEN / QB, BB * HH);
  attn_fwd<<<grid, dim3(256), 0, stream>>>(q, k, v, mask, out);
}

// Round 4
// 227.099 us; speedup vs baseline: 1.8339x; 1.1903x over previous
//
#include <hip/hip_runtime.h>
#include <hip/hip_bf16.h>

#define BB 2
#define HH 16
#define SLEN 2048
#define DD 64
#define QB 128
#define KB 64
#define NW 8
#define LOG2E 1.44269504088896340736f

typedef __attribute__((ext_vector_type(8))) short bf16x8;
typedef __attribute__((ext_vector_type(4))) float f32x4;

__device__ __forceinline__ unsigned short f2bf_rne(float x) {
  union { float f; unsigned u; } v; v.f = x;
  unsigned r = v.u + 0x7fffu + ((v.u >> 16) & 1u);
  return (unsigned short)(r >> 16);
}
__device__ __forceinline__ float bf2f(unsigned short h) {
  union { float f; unsigned u; } v; v.u = ((unsigned)h) << 16;
  return v.f;
}
// ushort-index into a [rows][64] LDS tile, XOR-swizzled: col bits 3..5 ^= row
// bits 0..2. 16B granules stay contiguous; 8 consecutive rows cover all 32
// banks for b128 ops.
__device__ __forceinline__ int swz(int row, int col) {
  return row * 64 + (col ^ ((row & 7) << 3));
}

__global__ __launch_bounds__(512) void attn_fwd(
    const float* __restrict__ q, const float* __restrict__ k,
    const float* __restrict__ v, const int* __restrict__ mask,
    float* __restrict__ out) {
  __shared__ unsigned short Khi[KB * DD];    // [t][d] hi bf16 (truncated)
  __shared__ unsigned short Klo[KB * DD];    // [t][d] lo bf16
  __shared__ unsigned short VT[DD * KB];     // [d][t] bf16
  __shared__ unsigned short Pl[NW][16 * KB]; // per-wave P tile [qrow][t]

  const int tid = threadIdx.x;
  const int w = tid >> 6;        // wave 0..7
  const int l = tid & 63;        // lane
  const int lg = l >> 4;         // lane group 0..3
  const int ln = l & 15;

  const int qt = blockIdx.x;     // query tile 0..15
  const int bh = blockIdx.y;     // 0..31
  const int b = bh / HH;

  const float* qbase = q + ((size_t)bh * SLEN + (size_t)qt * QB) * DD;
  const float* kbase = k + (size_t)bh * DD * SLEN;   // key is [D][S]
  const float* vbase = v + (size_t)bh * SLEN * DD;
  float* obase = out + ((size_t)bh * SLEN + (size_t)qt * QB) * DD;

  // staging roles (512 threads, 64x64 tiles):
  //   K: lane owns key-index t, 8 d's per wave.  V: lane owns d, 8 t's/wave.
  const int st_t = tid & 63;
  const int st_d0 = (tid >> 6) * 8;
  const int sv_d = tid & 63;
  const int sv_t0 = (tid >> 6) * 8;

  // ---- Q fragments in registers (hi/lo split), rows w*16+ln ----
  bf16x8 qhi[2], qlo[2];
  {
    const float* qrow = qbase + (size_t)(w * 16 + ln) * DD;
#pragma unroll
    for (int c = 0; c < 2; ++c) {
      int d0 = c * 32 + lg * 8;
#pragma unroll
      for (int j = 0; j < 8; ++j) {
        float x = qrow[d0 + j];
        unsigned short hi = f2bf_rne(x);
        qhi[c][j] = (short)hi;
        qlo[c][j] = (short)f2bf_rne(x - bf2f(hi));
      }
    }
  }

  // ---- per-thread mask additive (q = w*16 + ln), pre-scaled by log2(e) ----
  const float addv =
      mask[b * SLEN + qt * QB + w * 16 + ln] ? 0.0f : -1e12f * LOG2E;
  const float SC = 0.125f * LOG2E;  // 1/sqrt(64) * log2(e)

  f32x4 oacc[4];
#pragma unroll
  for (int nt = 0; nt < 4; ++nt) oacc[nt] = (f32x4){0.f, 0.f, 0.f, 0.f};
  float mrun = -INFINITY, lrun = 0.f;

  for (int kt = 0; kt < SLEN / KB; ++kt) {
    const int t0 = kt * KB;
    __syncthreads();  // prior tile's LDS reads done before overwrite

    // ---- stage K: column loads (coalesced), trunc hi/lo, b128 writes ----
    bf16x8 khiv, klov, vv;
#pragma unroll
    for (int j = 0; j < 8; ++j) {
      float x = kbase[(size_t)(st_d0 + j) * SLEN + t0 + st_t];
      unsigned short hi = (unsigned short)(__float_as_uint(x) >> 16);
      khiv[j] = (short)hi;
      klov[j] = (short)(unsigned short)(__float_as_uint(x - bf2f(hi)) >> 16);
    }
    // ---- stage V: coalesced along d, RNE, b128 write ----
#pragma unroll
    for (int j = 0; j < 8; ++j)
      vv[j] = (short)f2bf_rne(vbase[(size_t)(t0 + sv_t0 + j) * DD + sv_d]);

    *reinterpret_cast<bf16x8*>(&Khi[swz(st_t, st_d0)]) = khiv;
    *reinterpret_cast<bf16x8*>(&Klo[swz(st_t, st_d0)]) = klov;
    *reinterpret_cast<bf16x8*>(&VT[swz(sv_d, sv_t0)]) = vv;
    __syncthreads();

    // ---- S^T = K Q^T (swapped operands; hi/lo split, 3 MFMAs each) ----
    // C layout: row = t = nt*16 + lg*4 + r, col = q = ln.
    f32x4 sacc[4];
#pragma unroll
    for (int nt = 0; nt < 4; ++nt) sacc[nt] = (f32x4){0.f, 0.f, 0.f, 0.f};
#pragma unroll
    for (int c = 0; c < 2; ++c) {
      int d0 = c * 32 + lg * 8;
#pragma unroll
      for (int nt = 0; nt < 4; ++nt) {
        bf16x8 bhf = *reinterpret_cast<bf16x8*>(&Khi[swz(nt * 16 + ln, d0)]);
        bf16x8 blf = *reinterpret_cast<bf16x8*>(&Klo[swz(nt * 16 + ln, d0)]);
        sacc[nt] = __builtin_amdgcn_mfma_f32_16x16x32_bf16(bhf, qhi[c], sacc[nt], 0, 0, 0);
        sacc[nt] = __builtin_amdgcn_mfma_f32_16x16x32_bf16(bhf, qlo[c], sacc[nt], 0, 0, 0);
        sacc[nt] = __builtin_amdgcn_mfma_f32_16x16x32_bf16(blf, qhi[c], sacc[nt], 0, 0, 0);
      }
    }

    // ---- online softmax, fully per-thread (q = ln) ----
    float sv[4][4];
    float rm = -INFINITY;
#pragma unroll
    for (int nt = 0; nt < 4; ++nt)
#pragma unroll
      for (int r = 0; r < 4; ++r) {
        float x = sacc[nt][r] * SC + addv;
        sv[nt][r] = x;
        rm = fmaxf(rm, x);
      }
    rm = fmaxf(rm, __shfl_xor(rm, 16, 64));
    rm = fmaxf(rm, __shfl_xor(rm, 32, 64));
    float mnew = fmaxf(mrun, rm);
    float sf = exp2f(mrun - mnew);
    mrun = mnew;
    float rs = 0.f;
#pragma unroll
    for (int nt = 0; nt < 4; ++nt)
#pragma unroll
      for (int r = 0; r < 4; ++r) {
        float p = exp2f(sv[nt][r] - mnew);
        sv[nt][r] = p;
        rs += p;
      }
    rs += __shfl_xor(rs, 16, 64);
    rs += __shfl_xor(rs, 32, 64);
    lrun = lrun * sf + rs;
    // broadcast sf to this thread's accumulator rows (q = lg*4 + r)
    float sfb[4];
#pragma unroll
    for (int r = 0; r < 4; ++r)
      sfb[r] = __shfl(sf, (l & 48) | (lg * 4 + r), 64);
#pragma unroll
    for (int nt = 0; nt < 4; ++nt)
#pragma unroll
      for (int r = 0; r < 4; ++r) oacc[nt][r] *= sfb[r];

    // ---- P -> LDS (wave-private, packed b64 writes; lgkmcnt orders RAW) ----
#pragma unroll
    for (int nt = 0; nt < 4; ++nt) {
      unsigned u0 = (unsigned)f2bf_rne(sv[nt][0]) |
                    ((unsigned)f2bf_rne(sv[nt][1]) << 16);
      unsigned u1 = (unsigned)f2bf_rne(sv[nt][2]) |
                    ((unsigned)f2bf_rne(sv[nt][3]) << 16);
      uint2 pw; pw.x = u0; pw.y = u1;
      *reinterpret_cast<uint2*>(&Pl[w][swz(ln, nt * 16 + lg * 4)]) = pw;
    }

    // ---- O += P V ----
#pragma unroll
    for (int c = 0; c < 2; ++c) {
      int tc = c * 32 + lg * 8;
      bf16x8 pa = *reinterpret_cast<bf16x8*>(&Pl[w][swz(ln, tc)]);
#pragma unroll
      for (int nt = 0; nt < 4; ++nt) {
        bf16x8 vb = *reinterpret_cast<bf16x8*>(&VT[swz(nt * 16 + ln, tc)]);
        oacc[nt] = __builtin_amdgcn_mfma_f32_16x16x32_bf16(pa, vb, oacc[nt], 0, 0, 0);
      }
    }
  }

  // ---- epilogue: divide by row sum (broadcast lrun to acc rows), store ----
  float lr[4];
#pragma unroll
  for (int r = 0; r < 4; ++r)
    lr[r] = __shfl(lrun, (l & 48) | (lg * 4 + r), 64);
#pragma unroll
  for (int nt = 0; nt < 4; ++nt)
#pragma unroll
    for (int r = 0; r < 4; ++r) {
      obase[(size_t)(w * 16 + lg * 4 + r) * DD + nt * 16 + ln] =
          oacc[nt][r] / lr[r];
    }
}

extern "C" void kernel_launch(void* const* d_in, const int* in_sizes, int n_in,
                              void* d_out, int out_size, void* d_ws, size_t ws_size,
                              hipStream_t stream) {
  const float* q = (const float*)d_in[0];
  const float* k = (const float*)d_in[1];
  const float* v = (const float*)d_in[2];
  const int* mask = (const int*)d_in[3];
  float* out = (float*)d_out;
  dim3 grid(SLEN / QB, BB * HH);
  attn_fwd<<<grid, dim3(512), 0, stream>>>(q, k, v, mask, out);
}

// Round 6
// 188.625 us; speedup vs baseline: 2.2079x; 1.2040x over previous
//
#include <hip/hip_runtime.h>
#include <hip/hip_bf16.h>

#define BB 2
#define HH 16
#define SLEN 2048
#define DD 64
#define QB 128
#define KB 64
#define NW 8
#define NT (SLEN / KB)   // 32 K-tiles
#define NBH (BB * HH)    // 32
#define LOG2E 1.44269504088896340736f

typedef __attribute__((ext_vector_type(8))) short bf16x8;
typedef __attribute__((ext_vector_type(4))) float f32x4;
typedef unsigned short u16;

__device__ __forceinline__ u16 f2bf_rne(float x) {
  union { float f; unsigned u; } v; v.f = x;
  unsigned r = v.u + 0x7fffu + ((v.u >> 16) & 1u);
  return (u16)(r >> 16);
}
__device__ __forceinline__ float bf2f(u16 h) {
  union { float f; unsigned u; } v; v.u = ((unsigned)h) << 16;
  return v.f;
}
// packed f32->bf16 pair (lo -> bits[15:0], hi -> bits[31:16])
__device__ __forceinline__ unsigned cvt_pk_bf16(float lo, float hi) {
  unsigned r;
  asm("v_cvt_pk_bf16_f32 %0, %1, %2" : "=v"(r) : "v"(lo), "v"(hi));
  return r;
}
// ushort-index into a [rows][64] tile, XOR-swizzled: col bits 3..5 ^= row
// bits 0..2. 16B granules stay contiguous; 8 consecutive rows cover all 32
// banks for b128 ops.
__device__ __forceinline__ int swz(int row, int col) {
  return row * 64 + (col ^ ((row & 7) << 3));
}
// async 16B global->LDS copy; LDS dest = base + lane*16 (wave-linear)
__device__ __forceinline__ void gload_lds16(const u16* g, u16* l) {
  __builtin_amdgcn_global_load_lds(
      (const __attribute__((address_space(1))) unsigned int*)g,
      (__attribute__((address_space(3))) unsigned int*)l, 16, 0, 0);
}

// ---------------- pre-pass: K fp32 [bh][d][t] -> ws hi/lo bf16 [bh][t][d'] --
__global__ __launch_bounds__(256) void conv_k(const float* __restrict__ k,
                                              u16* __restrict__ wsKhi,
                                              u16* __restrict__ wsKlo) {
  const int wv = blockIdx.x * 4 + (threadIdx.x >> 6);  // 0..1023
  const int l = threadIdx.x & 63;
  const int bh = wv >> 5;
  const int t = (wv & 31) * 64 + l;
  const float* kb = k + (size_t)bh * DD * SLEN;
  u16* oh = wsKhi + ((size_t)bh * SLEN + t) * DD;
  u16* ol = wsKlo + ((size_t)bh * SLEN + t) * DD;
  const int sw = (t & 7) << 3;
#pragma unroll
  for (int g = 0; g < 8; ++g) {
    const int d0 = g * 8;
    bf16x8 hv, lv;
#pragma unroll
    for (int j = 0; j < 8; ++j) {
      float x = kb[(size_t)(d0 + j) * SLEN + t];  // coalesced across lanes
      u16 hi = (u16)(__float_as_uint(x) >> 16);   // truncation split
      hv[j] = (short)hi;
      lv[j] = (short)(u16)(__float_as_uint(x - bf2f(hi)) >> 16);
    }
    *reinterpret_cast<bf16x8*>(&oh[d0 ^ sw]) = hv;
    *reinterpret_cast<bf16x8*>(&ol[d0 ^ sw]) = lv;
  }
}

// ---------------- pre-pass: V fp32 [bh][t][d] -> ws bf16 [bh][kt][d][t'] ----
__global__ __launch_bounds__(256) void conv_v(const float* __restrict__ v,
                                              u16* __restrict__ wsVT) {
  const int wv = blockIdx.x * 4 + (threadIdx.x >> 6);  // 0..1023
  const int l = threadIdx.x & 63;                      // = d
  const int bh = wv >> 5;
  const int kt = wv & 31;
  const float* vb = v + ((size_t)bh * SLEN + (size_t)kt * KB) * DD;
  u16* ov = wsVT + (((size_t)bh * NT + kt) * KB + l) * DD;  // row d=l of tile
  const int sw = (l & 7) << 3;
#pragma unroll
  for (int g = 0; g < 8; ++g) {
    const int t0l = g * 8;
    bf16x8 vv;
#pragma unroll
    for (int j = 0; j < 8; ++j)
      vv[j] = (short)f2bf_rne(vb[(size_t)(t0l + j) * DD + l]);  // coalesced
    *reinterpret_cast<bf16x8*>(&ov[t0l ^ sw]) = vv;
  }
}

// ---------------- main: flash attention, async double-buffered staging ------
__global__ __launch_bounds__(512) void attn_fwd_pre(
    const float* __restrict__ q, const u16* __restrict__ wsKhi,
    const u16* __restrict__ wsKlo, const u16* __restrict__ wsVT,
    const int* __restrict__ mask, float* __restrict__ out) {
  __shared__ u16 KhiL[2][KB * DD];
  __shared__ u16 KloL[2][KB * DD];
  __shared__ u16 VTL[2][DD * KB];
  __shared__ u16 Pl[NW][16 * KB];

  const int tid = threadIdx.x;
  const int w = tid >> 6, l = tid & 63, lg = l >> 4, ln = l & 15;

  // XCD-contiguous remap (512 % 8 == 0 -> bijective): each XCD gets 64
  // consecutive sbids = 4 full bh panels -> K/V L2 reuse within an XCD.
  const int bid = blockIdx.x;
  const int sbid = (bid & 7) * 64 + (bid >> 3);
  const int qt = sbid & 15;
  const int bh = sbid >> 4;
  const int b = bh / HH;

  const float* qbase = q + ((size_t)bh * SLEN + (size_t)qt * QB) * DD;
  const u16* gKhi = wsKhi + (size_t)bh * SLEN * DD;
  const u16* gKlo = wsKlo + (size_t)bh * SLEN * DD;
  const u16* gVT = wsVT + (size_t)bh * NT * (KB * DD);
  float* obase = out + ((size_t)bh * SLEN + (size_t)qt * QB) * DD;

  const int co = tid * 8;  // this thread's 16B chunk (ushort idx) in a tile

  // issue one tile's async copies (3 x 16B per thread; 8KB per array)
  auto issue = [&](int kt, int buf) {
    gload_lds16(gKhi + kt * (KB * DD) + co, &KhiL[buf][w * 512]);
    gload_lds16(gKlo + kt * (KB * DD) + co, &KloL[buf][w * 512]);
    gload_lds16(gVT + kt * (KB * DD) + co, &VTL[buf][w * 512]);
  };

  issue(0, 0);  // tile 0 in flight while we set up Q

  // ---- Q fragments in registers (hi/lo split), rows w*16+ln ----
  bf16x8 qhi[2], qlo[2];
  {
    const float* qrow = qbase + (size_t)(w * 16 + ln) * DD;
#pragma unroll
    for (int c = 0; c < 2; ++c) {
      int d0 = c * 32 + lg * 8;
#pragma unroll
      for (int j = 0; j < 8; ++j) {
        float x = qrow[d0 + j];
        u16 hi = f2bf_rne(x);
        qhi[c][j] = (short)hi;
        qlo[c][j] = (short)f2bf_rne(x - bf2f(hi));
      }
    }
  }

  // ---- per-thread mask additive (q = w*16 + ln), pre-scaled by log2(e) ----
  const float addv =
      mask[b * SLEN + qt * QB + w * 16 + ln] ? 0.0f : -1e12f * LOG2E;
  const float SC = 0.125f * LOG2E;  // 1/sqrt(64) * log2(e)

  f32x4 oacc[4];
#pragma unroll
  for (int nt = 0; nt < 4; ++nt) oacc[nt] = (f32x4){0.f, 0.f, 0.f, 0.f};
  float mrun = -INFINITY, lrun = 0.f;

  int cur = 0;
  for (int kt = 0; kt < NT; ++kt) {
    // prefetch next tile into the other buffer (safe: end-of-prev-iter
    // barrier guarantees all waves finished reading it), then wait for the
    // CURRENT tile only — 3 newest loads stay in flight across the barrier.
    if (kt + 1 < NT) {
      issue(kt + 1, cur ^ 1);
      asm volatile("s_waitcnt vmcnt(3)" ::: "memory");
    } else {
      asm volatile("s_waitcnt vmcnt(0)" ::: "memory");
    }
    __builtin_amdgcn_s_barrier();  // raw barrier: no vmcnt(0) drain

    // ---- S^T = K Q^T (swapped operands; hi/lo split, 3 MFMAs each) ----
    // C layout: row = t = nt*16 + lg*4 + r, col = q = ln.
    f32x4 sacc[4];
#pragma unroll
    for (int nt = 0; nt < 4; ++nt) sacc[nt] = (f32x4){0.f, 0.f, 0.f, 0.f};
    __builtin_amdgcn_s_setprio(1);
#pragma unroll
    for (int c = 0; c < 2; ++c) {
      int d0 = c * 32 + lg * 8;
#pragma unroll
      for (int nt = 0; nt < 4; ++nt) {
        bf16x8 bhf =
            *reinterpret_cast<bf16x8*>(&KhiL[cur][swz(nt * 16 + ln, d0)]);
        bf16x8 blf =
            *reinterpret_cast<bf16x8*>(&KloL[cur][swz(nt * 16 + ln, d0)]);
        sacc[nt] = __builtin_amdgcn_mfma_f32_16x16x32_bf16(bhf, qhi[c], sacc[nt], 0, 0, 0);
        sacc[nt] = __builtin_amdgcn_mfma_f32_16x16x32_bf16(bhf, qlo[c], sacc[nt], 0, 0, 0);
        sacc[nt] = __builtin_amdgcn_mfma_f32_16x16x32_bf16(blf, qhi[c], sacc[nt], 0, 0, 0);
      }
    }
    __builtin_amdgcn_s_setprio(0);

    // ---- online softmax, fully per-thread (q = ln) ----
    float sv[4][4];
    float rm = -INFINITY;
#pragma unroll
    for (int nt = 0; nt < 4; ++nt)
#pragma unroll
      for (int r = 0; r < 4; ++r) {
        float x = sacc[nt][r] * SC + addv;
        sv[nt][r] = x;
        rm = fmaxf(rm, x);
      }
    rm = fmaxf(rm, __shfl_xor(rm, 16, 64));
    rm = fmaxf(rm, __shfl_xor(rm, 32, 64));
    float mnew = fmaxf(mrun, rm);
    float sf = exp2f(mrun - mnew);
    mrun = mnew;
    float rs = 0.f;
#pragma unroll
    for (int nt = 0; nt < 4; ++nt)
#pragma unroll
      for (int r = 0; r < 4; ++r) {
        float p = exp2f(sv[nt][r] - mnew);
        sv[nt][r] = p;
        rs += p;
      }
    rs += __shfl_xor(rs, 16, 64);
    rs += __shfl_xor(rs, 32, 64);
    lrun = lrun * sf + rs;
    // broadcast sf to this thread's accumulator rows (q = lg*4 + r)
    float sfb[4];
#pragma unroll
    for (int r = 0; r < 4; ++r)
      sfb[r] = __shfl(sf, (l & 48) | (lg * 4 + r), 64);
#pragma unroll
    for (int nt = 0; nt < 4; ++nt)
#pragma unroll
      for (int r = 0; r < 4; ++r) oacc[nt][r] *= sfb[r];

    // ---- P -> LDS (wave-private, hw packed cvt; lgkmcnt orders RAW) ----
#pragma unroll
    for (int nt = 0; nt < 4; ++nt) {
      uint2 pw;
      pw.x = cvt_pk_bf16(sv[nt][0], sv[nt][1]);
      pw.y = cvt_pk_bf16(sv[nt][2], sv[nt][3]);
      *reinterpret_cast<uint2*>(&Pl[w][swz(ln, nt * 16 + lg * 4)]) = pw;
    }

    // ---- O += P V ----
    __builtin_amdgcn_s_setprio(1);
#pragma unroll
    for (int c = 0; c < 2; ++c) {
      int tc = c * 32 + lg * 8;
      bf16x8 pa = *reinterpret_cast<bf16x8*>(&Pl[w][swz(ln, tc)]);
#pragma unroll
      for (int nt = 0; nt < 4; ++nt) {
        bf16x8 vb =
            *reinterpret_cast<bf16x8*>(&VTL[cur][swz(nt * 16 + ln, tc)]);
        oacc[nt] = __builtin_amdgcn_mfma_f32_16x16x32_bf16(pa, vb, oacc[nt], 0, 0, 0);
      }
    }
    __builtin_amdgcn_s_setprio(0);

    __builtin_amdgcn_s_barrier();  // all waves done reading buf[cur]
    cur ^= 1;
  }

  // ---- epilogue: divide by row sum (broadcast lrun to acc rows), store ----
  float lr[4];
#pragma unroll
  for (int r = 0; r < 4; ++r)
    lr[r] = __shfl(lrun, (l & 48) | (lg * 4 + r), 64);
#pragma unroll
  for (int nt = 0; nt < 4; ++nt)
#pragma unroll
    for (int r = 0; r < 4; ++r) {
      obase[(size_t)(w * 16 + lg * 4 + r) * DD + nt * 16 + ln] =
          oacc[nt][r] / lr[r];
    }
}

// ---------------- fallback (round-4 kernel) if ws too small -----------------
__global__ __launch_bounds__(512) void attn_fwd_fb(
    const float* __restrict__ q, const float* __restrict__ k,
    const float* __restrict__ v, const int* __restrict__ mask,
    float* __restrict__ out) {
  __shared__ u16 Khi[KB * DD];
  __shared__ u16 Klo[KB * DD];
  __shared__ u16 VT[DD * KB];
  __shared__ u16 Pl[NW][16 * KB];

  const int tid = threadIdx.x;
  const int w = tid >> 6, l = tid & 63, lg = l >> 4, ln = l & 15;
  const int qt = blockIdx.x;
  const int bh = blockIdx.y;
  const int b = bh / HH;

  const float* qbase = q + ((size_t)bh * SLEN + (size_t)qt * QB) * DD;
  const float* kbase = k + (size_t)bh * DD * SLEN;
  const float* vbase = v + (size_t)bh * SLEN * DD;
  float* obase = out + ((size_t)bh * SLEN + (size_t)qt * QB) * DD;

  const int st_t = tid & 63;
  const int st_d0 = (tid >> 6) * 8;
  const int sv_d = tid & 63;
  const int sv_t0 = (tid >> 6) * 8;

  bf16x8 qhi[2], qlo[2];
  {
    const float* qrow = qbase + (size_t)(w * 16 + ln) * DD;
#pragma unroll
    for (int c = 0; c < 2; ++c) {
      int d0 = c * 32 + lg * 8;
#pragma unroll
      for (int j = 0; j < 8; ++j) {
        float x = qrow[d0 + j];
        u16 hi = f2bf_rne(x);
        qhi[c][j] = (short)hi;
        qlo[c][j] = (short)f2bf_rne(x - bf2f(hi));
      }
    }
  }
  const float addv =
      mask[b * SLEN + qt * QB + w * 16 + ln] ? 0.0f : -1e12f * LOG2E;
  const float SC = 0.125f * LOG2E;

  f32x4 oacc[4];
#pragma unroll
  for (int nt = 0; nt < 4; ++nt) oacc[nt] = (f32x4){0.f, 0.f, 0.f, 0.f};
  float mrun = -INFINITY, lrun = 0.f;

  for (int kt = 0; kt < NT; ++kt) {
    const int t0 = kt * KB;
    __syncthreads();
    bf16x8 khiv, klov, vv;
#pragma unroll
    for (int j = 0; j < 8; ++j) {
      float x = kbase[(size_t)(st_d0 + j) * SLEN + t0 + st_t];
      u16 hi = (u16)(__float_as_uint(x) >> 16);
      khiv[j] = (short)hi;
      klov[j] = (short)(u16)(__float_as_uint(x - bf2f(hi)) >> 16);
    }
#pragma unroll
    for (int j = 0; j < 8; ++j)
      vv[j] = (short)f2bf_rne(vbase[(size_t)(t0 + sv_t0 + j) * DD + sv_d]);
    *reinterpret_cast<bf16x8*>(&Khi[swz(st_t, st_d0)]) = khiv;
    *reinterpret_cast<bf16x8*>(&Klo[swz(st_t, st_d0)]) = klov;
    *reinterpret_cast<bf16x8*>(&VT[swz(sv_d, sv_t0)]) = vv;
    __syncthreads();

    f32x4 sacc[4];
#pragma unroll
    for (int nt = 0; nt < 4; ++nt) sacc[nt] = (f32x4){0.f, 0.f, 0.f, 0.f};
#pragma unroll
    for (int c = 0; c < 2; ++c) {
      int d0 = c * 32 + lg * 8;
#pragma unroll
      for (int nt = 0; nt < 4; ++nt) {
        bf16x8 bhf = *reinterpret_cast<bf16x8*>(&Khi[swz(nt * 16 + ln, d0)]);
        bf16x8 blf = *reinterpret_cast<bf16x8*>(&Klo[swz(nt * 16 + ln, d0)]);
        sacc[nt] = __builtin_amdgcn_mfma_f32_16x16x32_bf16(bhf, qhi[c], sacc[nt], 0, 0, 0);
        sacc[nt] = __builtin_amdgcn_mfma_f32_16x16x32_bf16(bhf, qlo[c], sacc[nt], 0, 0, 0);
        sacc[nt] = __builtin_amdgcn_mfma_f32_16x16x32_bf16(blf, qhi[c], sacc[nt], 0, 0, 0);
      }
    }
    float sv[4][4];
    float rm = -INFINITY;
#pragma unroll
    for (int nt = 0; nt < 4; ++nt)
#pragma unroll
      for (int r = 0; r < 4; ++r) {
        float x = sacc[nt][r] * SC + addv;
        sv[nt][r] = x;
        rm = fmaxf(rm, x);
      }
    rm = fmaxf(rm, __shfl_xor(rm, 16, 64));
    rm = fmaxf(rm, __shfl_xor(rm, 32, 64));
    float mnew = fmaxf(mrun, rm);
    float sf = exp2f(mrun - mnew);
    mrun = mnew;
    float rs = 0.f;
#pragma unroll
    for (int nt = 0; nt < 4; ++nt)
#pragma unroll
      for (int r = 0; r < 4; ++r) {
        float p = exp2f(sv[nt][r] - mnew);
        sv[nt][r] = p;
        rs += p;
      }
    rs += __shfl_xor(rs, 16, 64);
    rs += __shfl_xor(rs, 32, 64);
    lrun = lrun * sf + rs;
    float sfb[4];
#pragma unroll
    for (int r = 0; r < 4; ++r)
      sfb[r] = __shfl(sf, (l & 48) | (lg * 4 + r), 64);
#pragma unroll
    for (int nt = 0; nt < 4; ++nt)
#pragma unroll
      for (int r = 0; r < 4; ++r) oacc[nt][r] *= sfb[r];
#pragma unroll
    for (int nt = 0; nt < 4; ++nt) {
      uint2 pw;
      pw.x = cvt_pk_bf16(sv[nt][0], sv[nt][1]);
      pw.y = cvt_pk_bf16(sv[nt][2], sv[nt][3]);
      *reinterpret_cast<uint2*>(&Pl[w][swz(ln, nt * 16 + lg * 4)]) = pw;
    }
#pragma unroll
    for (int c = 0; c < 2; ++c) {
      int tc = c * 32 + lg * 8;
      bf16x8 pa = *reinterpret_cast<bf16x8*>(&Pl[w][swz(ln, tc)]);
#pragma unroll
      for (int nt = 0; nt < 4; ++nt) {
        bf16x8 vb = *reinterpret_cast<bf16x8*>(&VT[swz(nt * 16 + ln, tc)]);
        oacc[nt] = __builtin_amdgcn_mfma_f32_16x16x32_bf16(pa, vb, oacc[nt], 0, 0, 0);
      }
    }
  }
  float lr[4];
#pragma unroll
  for (int r = 0; r < 4; ++r)
    lr[r] = __shfl(lrun, (l & 48) | (lg * 4 + r), 64);
#pragma unroll
  for (int nt = 0; nt < 4; ++nt)
#pragma unroll
    for (int r = 0; r < 4; ++r) {
      obase[(size_t)(w * 16 + lg * 4 + r) * DD + nt * 16 + ln] =
          oacc[nt][r] / lr[r];
    }
}

extern "C" void kernel_launch(void* const* d_in, const int* in_sizes, int n_in,
                              void* d_out, int out_size, void* d_ws, size_t ws_size,
                              hipStream_t stream) {
  const float* q = (const float*)d_in[0];
  const float* k = (const float*)d_in[1];
  const float* v = (const float*)d_in[2];
  const int* mask = (const int*)d_in[3];
  float* out = (float*)d_out;

  const size_t nKV = (size_t)NBH * SLEN * DD;  // ushorts per array
  const size_t need = 3 * nKV * sizeof(u16);   // 25.2 MB
  if (ws_size >= need) {
    u16* wsKhi = (u16*)d_ws;
    u16* wsKlo = wsKhi + nKV;
    u16* wsVT = wsKlo + nKV;
    conv_k<<<256, 256, 0, stream>>>(k, wsKhi, wsKlo);
    conv_v<<<256, 256, 0, stream>>>(v, wsVT);
    attn_fwd_pre<<<512, 512, 0, stream>>>(q, wsKhi, wsKlo, wsVT, mask, out);
  } else {
    attn_fwd_fb<<<dim3(SLEN / QB, NBH), 512, 0, stream>>>(q, k, v, mask, out);
  }
}

// Round 7
// 180.880 us; speedup vs baseline: 2.3025x; 1.0428x over previous
//
#include <hip/hip_runtime.h>
#include <hip/hip_bf16.h>

#define BB 2
#define HH 16
#define SLEN 2048
#define DD 64
#define QB 128
#define KB 64
#define NW 8
#define NT (SLEN / KB)   // 32 K-tiles
#define NBH (BB * HH)    // 32
#define LOG2E 1.44269504088896340736f

typedef __attribute__((ext_vector_type(8))) short bf16x8;
typedef __attribute__((ext_vector_type(4))) float f32x4;
typedef unsigned short u16;

__device__ __forceinline__ u16 f2bf_rne(float x) {
  union { float f; unsigned u; } v; v.f = x;
  unsigned r = v.u + 0x7fffu + ((v.u >> 16) & 1u);
  return (u16)(r >> 16);
}
__device__ __forceinline__ float bf2f(u16 h) {
  union { float f; unsigned u; } v; v.u = ((unsigned)h) << 16;
  return v.f;
}
// packed f32->bf16 pair (lo -> bits[15:0], hi -> bits[31:16])
__device__ __forceinline__ unsigned cvt_pk_bf16(float lo, float hi) {
  unsigned r;
  asm("v_cvt_pk_bf16_f32 %0, %1, %2" : "=v"(r) : "v"(lo), "v"(hi));
  return r;
}
// ushort-index into a [rows][64] tile, XOR-swizzled: col bits 3..5 ^= row
// bits 0..2. 16B granules stay contiguous; 8 consecutive rows cover all 32
// banks for b128 ops.
__device__ __forceinline__ int swz(int row, int col) {
  return row * 64 + (col ^ ((row & 7) << 3));
}
// async 16B global->LDS copy; LDS dest = base + lane*16 (wave-linear)
__device__ __forceinline__ void gload_lds16(const u16* g, u16* l) {
  __builtin_amdgcn_global_load_lds(
      (const __attribute__((address_space(1))) unsigned int*)g,
      (__attribute__((address_space(3))) unsigned int*)l, 16, 0, 0);
}

// ---- pre-pass (single kernel): K fp32 [bh][d][t] -> hi/lo bf16 [bh][t][d~]
//      and V fp32 [bh][t][d] -> bf16 [bh][kt][d][t~]; full occupancy ----
__global__ __launch_bounds__(256) void conv_kv(const float* __restrict__ k,
                                               const float* __restrict__ v,
                                               u16* __restrict__ wsKhi,
                                               u16* __restrict__ wsKlo,
                                               u16* __restrict__ wsVT) {
  const int wv = blockIdx.x * 4 + (threadIdx.x >> 6);  // 0..16383
  const int l = threadIdx.x & 63;
  if (wv < 8192) {
    // K task: (bh, t-chunk, d-group). lane = t offset (coalesced loads).
    const int bh = wv >> 8;
    const int tc = (wv >> 3) & 31;
    const int g = wv & 7;
    const int t = tc * 64 + l;
    const float* kb = k + ((size_t)bh * DD + g * 8) * SLEN + t;
    bf16x8 hv, lv;
#pragma unroll
    for (int j = 0; j < 8; ++j) {
      float x = kb[(size_t)j * SLEN];
      u16 hi = (u16)(__float_as_uint(x) >> 16);  // truncation split
      hv[j] = (short)hi;
      lv[j] = (short)(u16)(__float_as_uint(x - bf2f(hi)) >> 16);
    }
    const size_t o = ((size_t)bh * SLEN + t) * DD + ((g * 8) ^ ((t & 7) << 3));
    *reinterpret_cast<bf16x8*>(&wsKhi[o]) = hv;
    *reinterpret_cast<bf16x8*>(&wsKlo[o]) = lv;
  } else {
    // V task: (bh, kt, t-group). lane = d (coalesced loads).
    const int wv2 = wv - 8192;
    const int bh = wv2 >> 8;
    const int kt = (wv2 >> 3) & 31;
    const int g = wv2 & 7;
    const float* vb = v + ((size_t)bh * SLEN + (size_t)kt * KB + g * 8) * DD + l;
    bf16x8 vv;
#pragma unroll
    for (int j = 0; j < 8; ++j)
      vv[j] = (short)f2bf_rne(vb[(size_t)j * DD]);
    const size_t o = (((size_t)bh * NT + kt) * KB + l) * DD +
                     ((g * 8) ^ ((l & 7) << 3));
    *reinterpret_cast<bf16x8*>(&wsVT[o]) = vv;
  }
}

// ---------------- main: flash attention, async double-buffered staging ------
__global__ __launch_bounds__(512) void attn_fwd_pre(
    const float* __restrict__ q, const u16* __restrict__ wsKhi,
    const u16* __restrict__ wsKlo, const u16* __restrict__ wsVT,
    const int* __restrict__ mask, float* __restrict__ out) {
  __shared__ u16 KhiL[2][KB * DD];
  __shared__ u16 KloL[2][KB * DD];
  __shared__ u16 VTL[2][DD * KB];
  __shared__ u16 Pl[NW][16 * KB];

  const int tid = threadIdx.x;
  const int w = tid >> 6, l = tid & 63, lg = l >> 4, ln = l & 15;

  // XCD-contiguous remap (512 % 8 == 0 -> bijective): each XCD gets 64
  // consecutive sbids = 4 full bh panels -> K/V L2 reuse within an XCD.
  const int bid = blockIdx.x;
  const int sbid = (bid & 7) * 64 + (bid >> 3);
  const int qt = sbid & 15;
  const int bh = sbid >> 4;
  const int b = bh / HH;

  const float* qbase = q + ((size_t)bh * SLEN + (size_t)qt * QB) * DD;
  const u16* gKhi = wsKhi + (size_t)bh * SLEN * DD;
  const u16* gKlo = wsKlo + (size_t)bh * SLEN * DD;
  const u16* gVT = wsVT + (size_t)bh * NT * (KB * DD);
  float* obase = out + ((size_t)bh * SLEN + (size_t)qt * QB) * DD;

  const int co = tid * 8;  // this thread's 16B chunk (ushort idx) in a tile

  // issue one tile's async copies (3 x 16B per thread; 8KB per array)
  auto issue = [&](int kt, int buf) {
    gload_lds16(gKhi + kt * (KB * DD) + co, &KhiL[buf][w * 512]);
    gload_lds16(gKlo + kt * (KB * DD) + co, &KloL[buf][w * 512]);
    gload_lds16(gVT + kt * (KB * DD) + co, &VTL[buf][w * 512]);
  };

  issue(0, 0);  // tile 0 in flight while we set up Q

  // ---- Q fragments in registers (hi/lo split), rows w*16+ln ----
  bf16x8 qhi[2], qlo[2];
  {
    const float* qrow = qbase + (size_t)(w * 16 + ln) * DD;
#pragma unroll
    for (int c = 0; c < 2; ++c) {
      int d0 = c * 32 + lg * 8;
#pragma unroll
      for (int j = 0; j < 8; ++j) {
        float x = qrow[d0 + j];
        u16 hi = f2bf_rne(x);
        qhi[c][j] = (short)hi;
        qlo[c][j] = (short)f2bf_rne(x - bf2f(hi));
      }
    }
  }

  // ---- per-thread mask additive (q = w*16 + ln), pre-scaled by log2(e) ----
  const float addv =
      mask[b * SLEN + qt * QB + w * 16 + ln] ? 0.0f : -1e12f * LOG2E;
  const float SC = 0.125f * LOG2E;  // 1/sqrt(64) * log2(e)

  f32x4 oacc[4];
#pragma unroll
  for (int nt = 0; nt < 4; ++nt) oacc[nt] = (f32x4){0.f, 0.f, 0.f, 0.f};
  float mrun = -INFINITY, lrun = 0.f;

  int cur = 0;
  for (int kt = 0; kt < NT; ++kt) {
    // prefetch next tile into the other buffer (safe: end-of-prev-iter
    // barrier guarantees all waves finished reading it), then wait for the
    // CURRENT tile only — 3 newest loads stay in flight across the barrier.
    if (kt + 1 < NT) {
      issue(kt + 1, cur ^ 1);
      asm volatile("s_waitcnt vmcnt(3)" ::: "memory");
    } else {
      asm volatile("s_waitcnt vmcnt(0)" ::: "memory");
    }
    __builtin_amdgcn_s_barrier();  // raw barrier: no vmcnt(0) drain

    // ---- S^T = K Q^T (swapped operands; hi/lo split, 3 MFMAs each) ----
    // C layout: row = t = nt*16 + lg*4 + r, col = q = ln.
    f32x4 sacc[4];
#pragma unroll
    for (int nt = 0; nt < 4; ++nt) sacc[nt] = (f32x4){0.f, 0.f, 0.f, 0.f};
    __builtin_amdgcn_s_setprio(1);
#pragma unroll
    for (int c = 0; c < 2; ++c) {
      int d0 = c * 32 + lg * 8;
#pragma unroll
      for (int nt = 0; nt < 4; ++nt) {
        bf16x8 bhf =
            *reinterpret_cast<bf16x8*>(&KhiL[cur][swz(nt * 16 + ln, d0)]);
        bf16x8 blf =
            *reinterpret_cast<bf16x8*>(&KloL[cur][swz(nt * 16 + ln, d0)]);
        sacc[nt] = __builtin_amdgcn_mfma_f32_16x16x32_bf16(bhf, qhi[c], sacc[nt], 0, 0, 0);
        sacc[nt] = __builtin_amdgcn_mfma_f32_16x16x32_bf16(bhf, qlo[c], sacc[nt], 0, 0, 0);
        sacc[nt] = __builtin_amdgcn_mfma_f32_16x16x32_bf16(blf, qhi[c], sacc[nt], 0, 0, 0);
      }
    }
    __builtin_amdgcn_s_setprio(0);

    // ---- online softmax, per-thread (q = ln), defer-max (THR=8) ----
    float sv[4][4];
#pragma unroll
    for (int nt = 0; nt < 4; ++nt)
#pragma unroll
      for (int r = 0; r < 4; ++r) sv[nt][r] = sacc[nt][r] * SC + addv;
    // tree max (depth 4, shorter dep chain than serial-15)
    float a0 = fmaxf(fmaxf(sv[0][0], sv[0][1]), fmaxf(sv[0][2], sv[0][3]));
    float a1 = fmaxf(fmaxf(sv[1][0], sv[1][1]), fmaxf(sv[1][2], sv[1][3]));
    float a2 = fmaxf(fmaxf(sv[2][0], sv[2][1]), fmaxf(sv[2][2], sv[2][3]));
    float a3 = fmaxf(fmaxf(sv[3][0], sv[3][1]), fmaxf(sv[3][2], sv[3][3]));
    float rm = fmaxf(fmaxf(a0, a1), fmaxf(a2, a3));
    rm = fmaxf(rm, __shfl_xor(rm, 16, 64));
    rm = fmaxf(rm, __shfl_xor(rm, 32, 64));
    // rescale only when some row's max grew by > 8 (exp2 headroom: P <= 256,
    // bf16-safe). Masked rows: rm == mrun exactly -> always skip.
    if (!__all(rm <= mrun + 8.f)) {
      float mnew = fmaxf(mrun, rm);
      float sf = exp2f(mrun - mnew);
      mrun = mnew;
      float sfb[4];
#pragma unroll
      for (int r = 0; r < 4; ++r)
        sfb[r] = __shfl(sf, (l & 48) | (lg * 4 + r), 64);
      lrun *= sf;
#pragma unroll
      for (int nt = 0; nt < 4; ++nt)
#pragma unroll
        for (int r = 0; r < 4; ++r) oacc[nt][r] *= sfb[r];
    }
    float rs = 0.f;
#pragma unroll
    for (int nt = 0; nt < 4; ++nt)
#pragma unroll
      for (int r = 0; r < 4; ++r) {
        float p = exp2f(sv[nt][r] - mrun);
        sv[nt][r] = p;
        rs += p;
      }
    rs += __shfl_xor(rs, 16, 64);
    rs += __shfl_xor(rs, 32, 64);
    lrun += rs;

    // ---- P -> LDS (wave-private, hw packed cvt; lgkmcnt orders RAW) ----
#pragma unroll
    for (int nt = 0; nt < 4; ++nt) {
      uint2 pw;
      pw.x = cvt_pk_bf16(sv[nt][0], sv[nt][1]);
      pw.y = cvt_pk_bf16(sv[nt][2], sv[nt][3]);
      *reinterpret_cast<uint2*>(&Pl[w][swz(ln, nt * 16 + lg * 4)]) = pw;
    }

    // ---- O += P V ----
    __builtin_amdgcn_s_setprio(1);
#pragma unroll
    for (int c = 0; c < 2; ++c) {
      int tc = c * 32 + lg * 8;
      bf16x8 pa = *reinterpret_cast<bf16x8*>(&Pl[w][swz(ln, tc)]);
#pragma unroll
      for (int nt = 0; nt < 4; ++nt) {
        bf16x8 vb =
            *reinterpret_cast<bf16x8*>(&VTL[cur][swz(nt * 16 + ln, tc)]);
        oacc[nt] = __builtin_amdgcn_mfma_f32_16x16x32_bf16(pa, vb, oacc[nt], 0, 0, 0);
      }
    }
    __builtin_amdgcn_s_setprio(0);

    __builtin_amdgcn_s_barrier();  // all waves done reading buf[cur]
    cur ^= 1;
  }

  // ---- epilogue: divide by row sum (broadcast lrun to acc rows), store ----
  float lr[4];
#pragma unroll
  for (int r = 0; r < 4; ++r)
    lr[r] = __shfl(lrun, (l & 48) | (lg * 4 + r), 64);
#pragma unroll
  for (int nt = 0; nt < 4; ++nt)
#pragma unroll
    for (int r = 0; r < 4; ++r) {
      obase[(size_t)(w * 16 + lg * 4 + r) * DD + nt * 16 + ln] =
          oacc[nt][r] / lr[r];
    }
}

// ---------------- fallback (round-4 kernel) if ws too small -----------------
__global__ __launch_bounds__(512) void attn_fwd_fb(
    const float* __restrict__ q, const float* __restrict__ k,
    const float* __restrict__ v, const int* __restrict__ mask,
    float* __restrict__ out) {
  __shared__ u16 Khi[KB * DD];
  __shared__ u16 Klo[KB * DD];
  __shared__ u16 VT[DD * KB];
  __shared__ u16 Pl[NW][16 * KB];

  const int tid = threadIdx.x;
  const int w = tid >> 6, l = tid & 63, lg = l >> 4, ln = l & 15;
  const int qt = blockIdx.x;
  const int bh = blockIdx.y;
  const int b = bh / HH;

  const float* qbase = q + ((size_t)bh * SLEN + (size_t)qt * QB) * DD;
  const float* kbase = k + (size_t)bh * DD * SLEN;
  const float* vbase = v + (size_t)bh * SLEN * DD;
  float* obase = out + ((size_t)bh * SLEN + (size_t)qt * QB) * DD;

  const int st_t = tid & 63;
  const int st_d0 = (tid >> 6) * 8;
  const int sv_d = tid & 63;
  const int sv_t0 = (tid >> 6) * 8;

  bf16x8 qhi[2], qlo[2];
  {
    const float* qrow = qbase + (size_t)(w * 16 + ln) * DD;
#pragma unroll
    for (int c = 0; c < 2; ++c) {
      int d0 = c * 32 + lg * 8;
#pragma unroll
      for (int j = 0; j < 8; ++j) {
        float x = qrow[d0 + j];
        u16 hi = f2bf_rne(x);
        qhi[c][j] = (short)hi;
        qlo[c][j] = (short)f2bf_rne(x - bf2f(hi));
      }
    }
  }
  const float addv =
      mask[b * SLEN + qt * QB + w * 16 + ln] ? 0.0f : -1e12f * LOG2E;
  const float SC = 0.125f * LOG2E;

  f32x4 oacc[4];
#pragma unroll
  for (int nt = 0; nt < 4; ++nt) oacc[nt] = (f32x4){0.f, 0.f, 0.f, 0.f};
  float mrun = -INFINITY, lrun = 0.f;

  for (int kt = 0; kt < NT; ++kt) {
    const int t0 = kt * KB;
    __syncthreads();
    bf16x8 khiv, klov, vv;
#pragma unroll
    for (int j = 0; j < 8; ++j) {
      float x = kbase[(size_t)(st_d0 + j) * SLEN + t0 + st_t];
      u16 hi = (u16)(__float_as_uint(x) >> 16);
      khiv[j] = (short)hi;
      klov[j] = (short)(u16)(__float_as_uint(x - bf2f(hi)) >> 16);
    }
#pragma unroll
    for (int j = 0; j < 8; ++j)
      vv[j] = (short)f2bf_rne(vbase[(size_t)(t0 + sv_t0 + j) * DD + sv_d]);
    *reinterpret_cast<bf16x8*>(&Khi[swz(st_t, st_d0)]) = khiv;
    *reinterpret_cast<bf16x8*>(&Klo[swz(st_t, st_d0)]) = klov;
    *reinterpret_cast<bf16x8*>(&VT[swz(sv_d, sv_t0)]) = vv;
    __syncthreads();

    f32x4 sacc[4];
#pragma unroll
    for (int nt = 0; nt < 4; ++nt) sacc[nt] = (f32x4){0.f, 0.f, 0.f, 0.f};
#pragma unroll
    for (int c = 0; c < 2; ++c) {
      int d0 = c * 32 + lg * 8;
#pragma unroll
      for (int nt = 0; nt < 4; ++nt) {
        bf16x8 bhf = *reinterpret_cast<bf16x8*>(&Khi[swz(nt * 16 + ln, d0)]);
        bf16x8 blf = *reinterpret_cast<bf16x8*>(&Klo[swz(nt * 16 + ln, d0)]);
        sacc[nt] = __builtin_amdgcn_mfma_f32_16x16x32_bf16(bhf, qhi[c], sacc[nt], 0, 0, 0);
        sacc[nt] = __builtin_amdgcn_mfma_f32_16x16x32_bf16(bhf, qlo[c], sacc[nt], 0, 0, 0);
        sacc[nt] = __builtin_amdgcn_mfma_f32_16x16x32_bf16(blf, qhi[c], sacc[nt], 0, 0, 0);
      }
    }
    float sv[4][4];
    float rm = -INFINITY;
#pragma unroll
    for (int nt = 0; nt < 4; ++nt)
#pragma unroll
      for (int r = 0; r < 4; ++r) {
        float x = sacc[nt][r] * SC + addv;
        sv[nt][r] = x;
        rm = fmaxf(rm, x);
      }
    rm = fmaxf(rm, __shfl_xor(rm, 16, 64));
    rm = fmaxf(rm, __shfl_xor(rm, 32, 64));
    float mnew = fmaxf(mrun, rm);
    float sf = exp2f(mrun - mnew);
    mrun = mnew;
    float rs = 0.f;
#pragma unroll
    for (int nt = 0; nt < 4; ++nt)
#pragma unroll
      for (int r = 0; r < 4; ++r) {
        float p = exp2f(sv[nt][r] - mnew);
        sv[nt][r] = p;
        rs += p;
      }
    rs += __shfl_xor(rs, 16, 64);
    rs += __shfl_xor(rs, 32, 64);
    lrun = lrun * sf + rs;
    float sfb[4];
#pragma unroll
    for (int r = 0; r < 4; ++r)
      sfb[r] = __shfl(sf, (l & 48) | (lg * 4 + r), 64);
#pragma unroll
    for (int nt = 0; nt < 4; ++nt)
#pragma unroll
      for (int r = 0; r < 4; ++r) oacc[nt][r] *= sfb[r];
#pragma unroll
    for (int nt = 0; nt < 4; ++nt) {
      uint2 pw;
      pw.x = cvt_pk_bf16(sv[nt][0], sv[nt][1]);
      pw.y = cvt_pk_bf16(sv[nt][2], sv[nt][3]);
      *reinterpret_cast<uint2*>(&Pl[w][swz(ln, nt * 16 + lg * 4)]) = pw;
    }
#pragma unroll
    for (int c = 0; c < 2; ++c) {
      int tc = c * 32 + lg * 8;
      bf16x8 pa = *reinterpret_cast<bf16x8*>(&Pl[w][swz(ln, tc)]);
#pragma unroll
      for (int nt = 0; nt < 4; ++nt) {
        bf16x8 vb = *reinterpret_cast<bf16x8*>(&VT[swz(nt * 16 + ln, tc)]);
        oacc[nt] = __builtin_amdgcn_mfma_f32_16x16x32_bf16(pa, vb, oacc[nt], 0, 0, 0);
      }
    }
  }
  float lr[4];
#pragma unroll
  for (int r = 0; r < 4; ++r)
    lr[r] = __shfl(lrun, (l & 48) | (lg * 4 + r), 64);
#pragma unroll
  for (int nt = 0; nt < 4; ++nt)
#pragma unroll
    for (int r = 0; r < 4; ++r) {
      obase[(size_t)(w * 16 + lg * 4 + r) * DD + nt * 16 + ln] =
          oacc[nt][r] / lr[r];
    }
}

extern "C" void kernel_launch(void* const* d_in, const int* in_sizes, int n_in,
                              void* d_out, int out_size, void* d_ws, size_t ws_size,
                              hipStream_t stream) {
  const float* q = (const float*)d_in[0];
  const float* k = (const float*)d_in[1];
  const float* v = (const float*)d_in[2];
  const int* mask = (const int*)d_in[3];
  float* out = (float*)d_out;

  const size_t nKV = (size_t)NBH * SLEN * DD;  // ushorts per array
  const size_t need = 3 * nKV * sizeof(u16);   // 25.2 MB
  if (ws_size >= need) {
    u16* wsKhi = (u16*)d_ws;
    u16* wsKlo = wsKhi + nKV;
    u16* wsVT = wsKlo + nKV;
    conv_kv<<<4096, 256, 0, stream>>>(k, v, wsKhi, wsKlo, wsVT);
    attn_fwd_pre<<<512, 512, 0, stream>>>(q, wsKhi, wsKlo, wsVT, mask, out);
  } else {
    attn_fwd_fb<<<dim3(SLEN / QB, NBH), 512, 0, stream>>>(q, k, v, mask, out);
  }
}

// Round 11
// 177.106 us; speedup vs baseline: 2.3515x; 1.0213x over previous
//
#include <hip/hip_runtime.h>
#include <hip/hip_bf16.h>

#define BB 2
#define HH 16
#define SLEN 2048
#define DD 64
#define QB 128
#define KB 64
#define NW 8
#define NT (SLEN / KB)   // 32 K-tiles
#define NBH (BB * HH)    // 32
#define LOG2E 1.44269504088896340736f

typedef __attribute__((ext_vector_type(8))) short bf16x8;
typedef __attribute__((ext_vector_type(4))) float f32x4;
typedef unsigned short u16;

__device__ __forceinline__ u16 f2bf_rne(float x) {
  union { float f; unsigned u; } v; v.f = x;
  unsigned r = v.u + 0x7fffu + ((v.u >> 16) & 1u);
  return (u16)(r >> 16);
}
__device__ __forceinline__ float bf2f(u16 h) {
  union { float f; unsigned u; } v; v.u = ((unsigned)h) << 16;
  return v.f;
}
// packed f32->bf16 pair (lo -> bits[15:0], hi -> bits[31:16])
__device__ __forceinline__ unsigned cvt_pk_bf16(float lo, float hi) {
  unsigned r;
  asm("v_cvt_pk_bf16_f32 %0, %1, %2" : "=v"(r) : "v"(lo), "v"(hi));
  return r;
}
// ushort-index into a [rows][64] tile, XOR-swizzled: col bits 3..5 ^= row
// bits 0..2. 16B granules stay contiguous; 8 consecutive rows cover all 32
// banks for b128 ops.
__device__ __forceinline__ int swz(int row, int col) {
  return row * 64 + (col ^ ((row & 7) << 3));
}
// async 16B global->LDS copy; LDS dest = base + lane*16 (wave-linear)
__device__ __forceinline__ void gload_lds16(const u16* g, u16* l) {
  __builtin_amdgcn_global_load_lds(
      (const __attribute__((address_space(1))) unsigned int*)g,
      (__attribute__((address_space(3))) unsigned int*)l, 16, 0, 0);
}

// ---- pre-pass (single kernel, coalesced stores):
//      K fp32 [bh][d][t] -> hi/lo bf16 [bh][t][d~]
//      V fp32 [bh][t][d] -> bf16 [bh][kt][d][t~]
// Lane = (sub, g): each wave writes one contiguous 1KB span (the XOR
// granule-perm is a bijection within an 8-row octet). Writes the exact same
// values to the exact same addresses as the previous per-wave-granule
// version — only the lane->work mapping changed.
__global__ __launch_bounds__(256) void conv_kv(const float* __restrict__ k,
                                               const float* __restrict__ v,
                                               u16* __restrict__ wsKhi,
                                               u16* __restrict__ wsKlo,
                                               u16* __restrict__ wsVT) {
  const int wv = blockIdx.x * 4 + (threadIdx.x >> 6);  // 0..16383
  const int l = threadIdx.x & 63;
  const int sub = l >> 3;  // row within octet
  const int g = l & 7;     // 8-elem granule
  if (wv < 8192) {
    // K task: (bh, t-octet). lane covers (t = octet*8+sub, d-granule = g).
    const int bh = wv >> 8;
    const int t = ((wv & 255) << 3) + sub;
    const float* kb = k + ((size_t)bh * DD + g * 8) * SLEN + t;
    bf16x8 hv, lv;
#pragma unroll
    for (int j = 0; j < 8; ++j) {
      float x = kb[(size_t)j * SLEN];
      u16 hi = (u16)(__float_as_uint(x) >> 16);  // truncation split
      hv[j] = (short)hi;
      lv[j] = (short)(u16)(__float_as_uint(x - bf2f(hi)) >> 16);
    }
    const size_t o = ((size_t)bh * SLEN + t) * DD + ((g ^ sub) << 3);
    *reinterpret_cast<bf16x8*>(&wsKhi[o]) = hv;
    *reinterpret_cast<bf16x8*>(&wsKlo[o]) = lv;
  } else {
    // V task: (bh, kt, d-octet). lane covers (d = octet*8+sub, t-granule g).
    const int wv2 = wv - 8192;
    const int bh = wv2 >> 8;
    const int kt = (wv2 >> 3) & 31;
    const int d = ((wv2 & 7) << 3) + sub;
    const float* vb = v + ((size_t)bh * SLEN + kt * KB + g * 8) * DD + d;
    bf16x8 vv;
#pragma unroll
    for (int j = 0; j < 8; ++j)
      vv[j] = (short)f2bf_rne(vb[(size_t)j * DD]);
    const size_t o = (((size_t)bh * NT + kt) * KB + d) * DD + ((g ^ sub) << 3);
    *reinterpret_cast<bf16x8*>(&wsVT[o]) = vv;
  }
}

// ---------------- main: flash attention, async double-buffered staging ------
// (round-7-PASSING version: K=32 PV via wave-private LDS P tile)
__global__ __launch_bounds__(512) void attn_fwd_pre(
    const float* __restrict__ q, const u16* __restrict__ wsKhi,
    const u16* __restrict__ wsKlo, const u16* __restrict__ wsVT,
    const int* __restrict__ mask, float* __restrict__ out) {
  __shared__ u16 KhiL[2][KB * DD];
  __shared__ u16 KloL[2][KB * DD];
  __shared__ u16 VTL[2][DD * KB];
  __shared__ u16 Pl[NW][16 * KB];

  const int tid = threadIdx.x;
  const int w = tid >> 6, l = tid & 63, lg = l >> 4, ln = l & 15;

  // XCD-contiguous remap (512 % 8 == 0 -> bijective)
  const int bid = blockIdx.x;
  const int sbid = (bid & 7) * 64 + (bid >> 3);
  const int qt = sbid & 15;
  const int bh = sbid >> 4;
  const int b = bh / HH;

  const float* qbase = q + ((size_t)bh * SLEN + (size_t)qt * QB) * DD;
  const u16* gKhi = wsKhi + (size_t)bh * SLEN * DD;
  const u16* gKlo = wsKlo + (size_t)bh * SLEN * DD;
  const u16* gVT = wsVT + (size_t)bh * NT * (KB * DD);
  float* obase = out + ((size_t)bh * SLEN + (size_t)qt * QB) * DD;

  const int co = tid * 8;  // this thread's 16B chunk (ushort idx) in a tile

  auto issue = [&](int kt, int buf) {
    gload_lds16(gKhi + kt * (KB * DD) + co, &KhiL[buf][w * 512]);
    gload_lds16(gKlo + kt * (KB * DD) + co, &KloL[buf][w * 512]);
    gload_lds16(gVT + kt * (KB * DD) + co, &VTL[buf][w * 512]);
  };

  issue(0, 0);  // tile 0 in flight while we set up Q

  // ---- Q fragments in registers (hi/lo split), rows w*16+ln ----
  bf16x8 qhi[2], qlo[2];
  {
    const float* qrow = qbase + (size_t)(w * 16 + ln) * DD;
#pragma unroll
    for (int c = 0; c < 2; ++c) {
      int d0 = c * 32 + lg * 8;
#pragma unroll
      for (int j = 0; j < 8; ++j) {
        float x = qrow[d0 + j];
        u16 hi = f2bf_rne(x);
        qhi[c][j] = (short)hi;
        qlo[c][j] = (short)f2bf_rne(x - bf2f(hi));
      }
    }
  }

  const float addv =
      mask[b * SLEN + qt * QB + w * 16 + ln] ? 0.0f : -1e12f * LOG2E;
  const float SC = 0.125f * LOG2E;  // 1/sqrt(64) * log2(e)

  f32x4 oacc[4];
#pragma unroll
  for (int nt = 0; nt < 4; ++nt) oacc[nt] = (f32x4){0.f, 0.f, 0.f, 0.f};
  float mrun = -INFINITY, lrun = 0.f;

  int cur = 0;
  for (int kt = 0; kt < NT; ++kt) {
    if (kt + 1 < NT) {
      issue(kt + 1, cur ^ 1);
      asm volatile("s_waitcnt vmcnt(3)" ::: "memory");
    } else {
      asm volatile("s_waitcnt vmcnt(0)" ::: "memory");
    }
    __builtin_amdgcn_s_barrier();  // raw barrier: no vmcnt(0) drain

    // ---- S^T = K Q^T (swapped operands; hi/lo split, 3 MFMAs each) ----
    // C layout: row = t = nt*16 + lg*4 + r, col = q = ln.
    f32x4 sacc[4];
#pragma unroll
    for (int nt = 0; nt < 4; ++nt) sacc[nt] = (f32x4){0.f, 0.f, 0.f, 0.f};
    __builtin_amdgcn_s_setprio(1);
#pragma unroll
    for (int c = 0; c < 2; ++c) {
      int d0 = c * 32 + lg * 8;
#pragma unroll
      for (int nt = 0; nt < 4; ++nt) {
        bf16x8 bhf =
            *reinterpret_cast<bf16x8*>(&KhiL[cur][swz(nt * 16 + ln, d0)]);
        bf16x8 blf =
            *reinterpret_cast<bf16x8*>(&KloL[cur][swz(nt * 16 + ln, d0)]);
        sacc[nt] = __builtin_amdgcn_mfma_f32_16x16x32_bf16(bhf, qhi[c], sacc[nt], 0, 0, 0);
        sacc[nt] = __builtin_amdgcn_mfma_f32_16x16x32_bf16(bhf, qlo[c], sacc[nt], 0, 0, 0);
        sacc[nt] = __builtin_amdgcn_mfma_f32_16x16x32_bf16(blf, qhi[c], sacc[nt], 0, 0, 0);
      }
    }
    __builtin_amdgcn_s_setprio(0);

    // ---- online softmax, per-thread (q = ln), defer-max (THR=8) ----
    float sv[4][4];
#pragma unroll
    for (int nt = 0; nt < 4; ++nt)
#pragma unroll
      for (int r = 0; r < 4; ++r) sv[nt][r] = sacc[nt][r] * SC + addv;
    float a0 = fmaxf(fmaxf(sv[0][0], sv[0][1]), fmaxf(sv[0][2], sv[0][3]));
    float a1 = fmaxf(fmaxf(sv[1][0], sv[1][1]), fmaxf(sv[1][2], sv[1][3]));
    float a2 = fmaxf(fmaxf(sv[2][0], sv[2][1]), fmaxf(sv[2][2], sv[2][3]));
    float a3 = fmaxf(fmaxf(sv[3][0], sv[3][1]), fmaxf(sv[3][2], sv[3][3]));
    float rm = fmaxf(fmaxf(a0, a1), fmaxf(a2, a3));
    rm = fmaxf(rm, __shfl_xor(rm, 16, 64));
    rm = fmaxf(rm, __shfl_xor(rm, 32, 64));
    if (!__all(rm <= mrun + 8.f)) {
      float mnew = fmaxf(mrun, rm);
      float sf = exp2f(mrun - mnew);
      mrun = mnew;
      float sfb[4];
#pragma unroll
      for (int r = 0; r < 4; ++r)
        sfb[r] = __shfl(sf, (l & 48) | (lg * 4 + r), 64);
      lrun *= sf;
#pragma unroll
      for (int nt = 0; nt < 4; ++nt)
#pragma unroll
        for (int r = 0; r < 4; ++r) oacc[nt][r] *= sfb[r];
    }
    float rs = 0.f;
#pragma unroll
    for (int nt = 0; nt < 4; ++nt)
#pragma unroll
      for (int r = 0; r < 4; ++r) {
        float p = exp2f(sv[nt][r] - mrun);
        sv[nt][r] = p;
        rs += p;
      }
    rs += __shfl_xor(rs, 16, 64);
    rs += __shfl_xor(rs, 32, 64);
    lrun += rs;

    // ---- P -> LDS (wave-private, hw packed cvt; lgkmcnt orders RAW) ----
#pragma unroll
    for (int nt = 0; nt < 4; ++nt) {
      uint2 pw;
      pw.x = cvt_pk_bf16(sv[nt][0], sv[nt][1]);
      pw.y = cvt_pk_bf16(sv[nt][2], sv[nt][3]);
      *reinterpret_cast<uint2*>(&Pl[w][swz(ln, nt * 16 + lg * 4)]) = pw;
    }

    // ---- O += P V ----
    __builtin_amdgcn_s_setprio(1);
#pragma unroll
    for (int c = 0; c < 2; ++c) {
      int tc = c * 32 + lg * 8;
      bf16x8 pa = *reinterpret_cast<bf16x8*>(&Pl[w][swz(ln, tc)]);
#pragma unroll
      for (int nt = 0; nt < 4; ++nt) {
        bf16x8 vb =
            *reinterpret_cast<bf16x8*>(&VTL[cur][swz(nt * 16 + ln, tc)]);
        oacc[nt] = __builtin_amdgcn_mfma_f32_16x16x32_bf16(pa, vb, oacc[nt], 0, 0, 0);
      }
    }
    __builtin_amdgcn_s_setprio(0);

    __builtin_amdgcn_s_barrier();  // all waves done reading buf[cur]
    cur ^= 1;
  }

  // ---- epilogue: divide by row sum (broadcast lrun to acc rows), store ----
  float lr[4];
#pragma unroll
  for (int r = 0; r < 4; ++r)
    lr[r] = __shfl(lrun, (l & 48) | (lg * 4 + r), 64);
#pragma unroll
  for (int nt = 0; nt < 4; ++nt)
#pragma unroll
    for (int r = 0; r < 4; ++r) {
      obase[(size_t)(w * 16 + lg * 4 + r) * DD + nt * 16 + ln] =
          oacc[nt][r] / lr[r];
    }
}

// ---------------- fallback (round-4 kernel) if ws too small -----------------
__global__ __launch_bounds__(512) void attn_fwd_fb(
    const float* __restrict__ q, const float* __restrict__ k,
    const float* __restrict__ v, const int* __restrict__ mask,
    float* __restrict__ out) {
  __shared__ u16 Khi[KB * DD];
  __shared__ u16 Klo[KB * DD];
  __shared__ u16 VT[DD * KB];
  __shared__ u16 Pl[NW][16 * KB];

  const int tid = threadIdx.x;
  const int w = tid >> 6, l = tid & 63, lg = l >> 4, ln = l & 15;
  const int qt = blockIdx.x;
  const int bh = blockIdx.y;
  const int b = bh / HH;

  const float* qbase = q + ((size_t)bh * SLEN + (size_t)qt * QB) * DD;
  const float* kbase = k + (size_t)bh * DD * SLEN;
  const float* vbase = v + (size_t)bh * SLEN * DD;
  float* obase = out + ((size_t)bh * SLEN + (size_t)qt * QB) * DD;

  const int st_t = tid & 63;
  const int st_d0 = (tid >> 6) * 8;
  const int sv_d = tid & 63;
  const int sv_t0 = (tid >> 6) * 8;

  bf16x8 qhi[2], qlo[2];
  {
    const float* qrow = qbase + (size_t)(w * 16 + ln) * DD;
#pragma unroll
    for (int c = 0; c < 2; ++c) {
      int d0 = c * 32 + lg * 8;
#pragma unroll
      for (int j = 0; j < 8; ++j) {
        float x = qrow[d0 + j];
        u16 hi = f2bf_rne(x);
        qhi[c][j] = (short)hi;
        qlo[c][j] = (short)f2bf_rne(x - bf2f(hi));
      }
    }
  }
  const float addv =
      mask[b * SLEN + qt * QB + w * 16 + ln] ? 0.0f : -1e12f * LOG2E;
  const float SC = 0.125f * LOG2E;

  f32x4 oacc[4];
#pragma unroll
  for (int nt = 0; nt < 4; ++nt) oacc[nt] = (f32x4){0.f, 0.f, 0.f, 0.f};
  float mrun = -INFINITY, lrun = 0.f;

  for (int kt = 0; kt < NT; ++kt) {
    const int t0 = kt * KB;
    __syncthreads();
    bf16x8 khiv, klov, vv;
#pragma unroll
    for (int j = 0; j < 8; ++j) {
      float x = kbase[(size_t)(st_d0 + j) * SLEN + t0 + st_t];
      u16 hi = (u16)(__float_as_uint(x) >> 16);
      khiv[j] = (short)hi;
      klov[j] = (short)(u16)(__float_as_uint(x - bf2f(hi)) >> 16);
    }
#pragma unroll
    for (int j = 0; j < 8; ++j)
      vv[j] = (short)f2bf_rne(vbase[(size_t)(t0 + sv_t0 + j) * DD + sv_d]);
    *reinterpret_cast<bf16x8*>(&Khi[swz(st_t, st_d0)]) = khiv;
    *reinterpret_cast<bf16x8*>(&Klo[swz(st_t, st_d0)]) = klov;
    *reinterpret_cast<bf16x8*>(&VT[swz(sv_d, sv_t0)]) = vv;
    __syncthreads();

    f32x4 sacc[4];
#pragma unroll
    for (int nt = 0; nt < 4; ++nt) sacc[nt] = (f32x4){0.f, 0.f, 0.f, 0.f};
#pragma unroll
    for (int c = 0; c < 2; ++c) {
      int d0 = c * 32 + lg * 8;
#pragma unroll
      for (int nt = 0; nt < 4; ++nt) {
        bf16x8 bhf = *reinterpret_cast<bf16x8*>(&Khi[swz(nt * 16 + ln, d0)]);
        bf16x8 blf = *reinterpret_cast<bf16x8*>(&Klo[swz(nt * 16 + ln, d0)]);
        sacc[nt] = __builtin_amdgcn_mfma_f32_16x16x32_bf16(bhf, qhi[c], sacc[nt], 0, 0, 0);
        sacc[nt] = __builtin_amdgcn_mfma_f32_16x16x32_bf16(bhf, qlo[c], sacc[nt], 0, 0, 0);
        sacc[nt] = __builtin_amdgcn_mfma_f32_16x16x32_bf16(blf, qhi[c], sacc[nt], 0, 0, 0);
      }
    }
    float sv[4][4];
    float rm = -INFINITY;
#pragma unroll
    for (int nt = 0; nt < 4; ++nt)
#pragma unroll
      for (int r = 0; r < 4; ++r) {
        float x = sacc[nt][r] * SC + addv;
        sv[nt][r] = x;
        rm = fmaxf(rm, x);
      }
    rm = fmaxf(rm, __shfl_xor(rm, 16, 64));
    rm = fmaxf(rm, __shfl_xor(rm, 32, 64));
    float mnew = fmaxf(mrun, rm);
    float sf = exp2f(mrun - mnew);
    mrun = mnew;
    float rs = 0.f;
#pragma unroll
    for (int nt = 0; nt < 4; ++nt)
#pragma unroll
      for (int r = 0; r < 4; ++r) {
        float p = exp2f(sv[nt][r] - mnew);
        sv[nt][r] = p;
        rs += p;
      }
    rs += __shfl_xor(rs, 16, 64);
    rs += __shfl_xor(rs, 32, 64);
    lrun = lrun * sf + rs;
    float sfb[4];
#pragma unroll
    for (int r = 0; r < 4; ++r)
      sfb[r] = __shfl(sf, (l & 48) | (lg * 4 + r), 64);
#pragma unroll
    for (int nt = 0; nt < 4; ++nt)
#pragma unroll
      for (int r = 0; r < 4; ++r) oacc[nt][r] *= sfb[r];
#pragma unroll
    for (int nt = 0; nt < 4; ++nt) {
      uint2 pw;
      pw.x = cvt_pk_bf16(sv[nt][0], sv[nt][1]);
      pw.y = cvt_pk_bf16(sv[nt][2], sv[nt][3]);
      *reinterpret_cast<uint2*>(&Pl[w][swz(ln, nt * 16 + lg * 4)]) = pw;
    }
#pragma unroll
    for (int c = 0; c < 2; ++c) {
      int tc = c * 32 + lg * 8;
      bf16x8 pa = *reinterpret_cast<bf16x8*>(&Pl[w][swz(ln, tc)]);
#pragma unroll
      for (int nt = 0; nt < 4; ++nt) {
        bf16x8 vb = *reinterpret_cast<bf16x8*>(&VT[swz(nt * 16 + ln, tc)]);
        oacc[nt] = __builtin_amdgcn_mfma_f32_16x16x32_bf16(pa, vb, oacc[nt], 0, 0, 0);
      }
    }
  }
  float lr[4];
#pragma unroll
  for (int r = 0; r < 4; ++r)
    lr[r] = __shfl(lrun, (l & 48) | (lg * 4 + r), 64);
#pragma unroll
  for (int nt = 0; nt < 4; ++nt)
#pragma unroll
    for (int r = 0; r < 4; ++r) {
      obase[(size_t)(w * 16 + lg * 4 + r) * DD + nt * 16 + ln] =
          oacc[nt][r] / lr[r];
    }
}

extern "C" void kernel_launch(void* const* d_in, const int* in_sizes, int n_in,
                              void* d_out, int out_size, void* d_ws, size_t ws_size,
                              hipStream_t stream) {
  const float* q = (const float*)d_in[0];
  const float* k = (const float*)d_in[1];
  const float* v = (const float*)d_in[2];
  const int* mask = (const int*)d_in[3];
  float* out = (float*)d_out;

  const size_t nKV = (size_t)NBH * SLEN * DD;  // ushorts per array
  const size_t need = 3 * nKV * sizeof(u16);   // 25.2 MB
  if (ws_size >= need) {
    u16* wsKhi = (u16*)d_ws;
    u16* wsKlo = wsKhi + nKV;
    u16* wsVT = wsKlo + nKV;
    conv_kv<<<4096, 256, 0, stream>>>(k, v, wsKhi, wsKlo, wsVT);
    attn_fwd_pre<<<512, 512, 0, stream>>>(q, wsKhi, wsKlo, wsVT, mask, out);
  } else {
    attn_fwd_fb<<<dim3(SLEN / QB, NBH), 512, 0, stream>>>(q, k, v, mask, out);
  }
}

// Round 13
// 176.755 us; speedup vs baseline: 2.3562x; 1.0020x over previous
//
#include <hip/hip_runtime.h>
#include <hip/hip_bf16.h>

#define BB 2
#define HH 16
#define SLEN 2048
#define DD 64
#define QB 128
#define KB 64
#define NW 8
#define NT (SLEN / KB)   // 32 K-tiles
#define NBH (BB * HH)    // 32
#define LOG2E 1.44269504088896340736f
#define SCK (0.125f * LOG2E)  // softmax scale folded into K at conversion

typedef __attribute__((ext_vector_type(8))) short bf16x8;
typedef __attribute__((ext_vector_type(4))) float f32x4;
typedef unsigned short u16;

__device__ __forceinline__ u16 f2bf_rne(float x) {
  union { float f; unsigned u; } v; v.f = x;
  unsigned r = v.u + 0x7fffu + ((v.u >> 16) & 1u);
  return (u16)(r >> 16);
}
__device__ __forceinline__ float bf2f(u16 h) {
  union { float f; unsigned u; } v; v.u = ((unsigned)h) << 16;
  return v.f;
}
// packed f32->bf16 pair (lo -> bits[15:0], hi -> bits[31:16])
__device__ __forceinline__ unsigned cvt_pk_bf16(float lo, float hi) {
  unsigned r;
  asm("v_cvt_pk_bf16_f32 %0, %1, %2" : "=v"(r) : "v"(lo), "v"(hi));
  return r;
}
// ushort-index into a [rows][64] tile, XOR-swizzled: col bits 3..5 ^= row
// bits 0..2. 16B granules stay contiguous; 8 consecutive rows cover all 32
// banks for b128 ops.
__device__ __forceinline__ int swz(int row, int col) {
  return row * 64 + (col ^ ((row & 7) << 3));
}
// async 16B global->LDS copy; LDS dest = base + lane*16 (wave-linear)
__device__ __forceinline__ void gload_lds16(const u16* g, u16* l) {
  __builtin_amdgcn_global_load_lds(
      (const __attribute__((address_space(1))) unsigned int*)g,
      (__attribute__((address_space(3))) unsigned int*)l, 16, 0, 0);
}

// ---- pre-pass (single kernel, coalesced stores):
//      K fp32 [bh][d][t] -> hi/lo bf16 of (K * SCK)  [bh][t][d~]
//      V fp32 [bh][t][d] -> bf16 [bh][kt][d][t~]
// Lane = (sub, g): each wave writes one contiguous 1KB span (XOR granule
// perm is a bijection within an 8-row octet).
__global__ __launch_bounds__(256) void conv_kv(const float* __restrict__ k,
                                               const float* __restrict__ v,
                                               u16* __restrict__ wsKhi,
                                               u16* __restrict__ wsKlo,
                                               u16* __restrict__ wsVT) {
  const int wv = blockIdx.x * 4 + (threadIdx.x >> 6);  // 0..16383
  const int l = threadIdx.x & 63;
  const int sub = l >> 3;  // row within octet
  const int g = l & 7;     // 8-elem granule
  if (wv < 8192) {
    // K task: (bh, t-octet). lane covers (t = octet*8+sub, d-granule = g).
    const int bh = wv >> 8;
    const int t = ((wv & 255) << 3) + sub;
    const float* kb = k + ((size_t)bh * DD + g * 8) * SLEN + t;
    bf16x8 hv, lv;
#pragma unroll
    for (int j = 0; j < 8; ++j) {
      float x = kb[(size_t)j * SLEN] * SCK;      // scale folded here
      u16 hi = (u16)(__float_as_uint(x) >> 16);  // truncation split
      hv[j] = (short)hi;
      lv[j] = (short)(u16)(__float_as_uint(x - bf2f(hi)) >> 16);
    }
    const size_t o = ((size_t)bh * SLEN + t) * DD + ((g ^ sub) << 3);
    *reinterpret_cast<bf16x8*>(&wsKhi[o]) = hv;
    *reinterpret_cast<bf16x8*>(&wsKlo[o]) = lv;
  } else {
    // V task: (bh, kt, d-octet). lane covers (d = octet*8+sub, t-granule g).
    const int wv2 = wv - 8192;
    const int bh = wv2 >> 8;
    const int kt = (wv2 >> 3) & 31;
    const int d = ((wv2 & 7) << 3) + sub;
    const float* vb = v + ((size_t)bh * SLEN + kt * KB + g * 8) * DD + d;
    bf16x8 vv;
#pragma unroll
    for (int j = 0; j < 8; ++j)
      vv[j] = (short)f2bf_rne(vb[(size_t)j * DD]);
    const size_t o = (((size_t)bh * NT + kt) * KB + d) * DD + ((g ^ sub) << 3);
    *reinterpret_cast<bf16x8*>(&wsVT[o]) = vv;
  }
}

// ---------------- main: flash attention, async double-buffered staging ------
// Mask folded into Q (masked q-rows zeroed -> scores exactly 0 -> uniform
// weights, matching the reference's fp32 -1e12 absorption). K pre-scaled by
// SCK in conv -> softmax is pure {max, add, exp2}. kt-loop unrolled x2 for
// compile-time LDS buffer indices.
__global__ __launch_bounds__(512) void attn_fwd_pre(
    const float* __restrict__ q, const u16* __restrict__ wsKhi,
    const u16* __restrict__ wsKlo, const u16* __restrict__ wsVT,
    const int* __restrict__ mask, float* __restrict__ out) {
  __shared__ u16 KhiL[2][KB * DD];
  __shared__ u16 KloL[2][KB * DD];
  __shared__ u16 VTL[2][DD * KB];
  __shared__ u16 Pl[NW][16 * KB];

  const int tid = threadIdx.x;
  const int w = tid >> 6, l = tid & 63, lg = l >> 4, ln = l & 15;

  // XCD-contiguous remap (512 % 8 == 0 -> bijective)
  const int bid = blockIdx.x;
  const int sbid = (bid & 7) * 64 + (bid >> 3);
  const int qt = sbid & 15;
  const int bh = sbid >> 4;
  const int b = bh / HH;

  const float* qbase = q + ((size_t)bh * SLEN + (size_t)qt * QB) * DD;
  const u16* gKhi = wsKhi + (size_t)bh * SLEN * DD;
  const u16* gKlo = wsKlo + (size_t)bh * SLEN * DD;
  const u16* gVT = wsVT + (size_t)bh * NT * (KB * DD);
  float* obase = out + ((size_t)bh * SLEN + (size_t)qt * QB) * DD;

  const int co = tid * 8;  // this thread's 16B chunk (ushort idx) in a tile

  auto issue = [&](int kt, int buf) {
    gload_lds16(gKhi + kt * (KB * DD) + co, &KhiL[buf][w * 512]);
    gload_lds16(gKlo + kt * (KB * DD) + co, &KloL[buf][w * 512]);
    gload_lds16(gVT + kt * (KB * DD) + co, &VTL[buf][w * 512]);
  };

  issue(0, 0);  // tile 0 in flight while we set up Q

  // ---- mask -> Q-row zeroing (per-thread q-row = w*16 + ln) ----
  const float mb =
      mask[b * SLEN + qt * QB + w * 16 + ln] ? 1.0f : 0.0f;

  // ---- Q fragments in registers (hi/lo split), rows w*16+ln ----
  bf16x8 qhi[2], qlo[2];
  {
    const float* qrow = qbase + (size_t)(w * 16 + ln) * DD;
#pragma unroll
    for (int c = 0; c < 2; ++c) {
      int d0 = c * 32 + lg * 8;
#pragma unroll
      for (int j = 0; j < 8; ++j) {
        float x = qrow[d0 + j] * mb;
        u16 hi = f2bf_rne(x);
        qhi[c][j] = (short)hi;
        qlo[c][j] = (short)f2bf_rne(x - bf2f(hi));
      }
    }
  }

  f32x4 oacc[4];
#pragma unroll
  for (int nt = 0; nt < 4; ++nt) oacc[nt] = (f32x4){0.f, 0.f, 0.f, 0.f};
  float mrun = -INFINITY, lrun = 0.f;

  auto tile = [&](int kt, int cur) {
    if (kt + 1 < NT) {
      issue(kt + 1, cur ^ 1);
      asm volatile("s_waitcnt vmcnt(3)" ::: "memory");
    } else {
      asm volatile("s_waitcnt vmcnt(0)" ::: "memory");
    }
    __builtin_amdgcn_s_barrier();  // raw barrier: no vmcnt(0) drain

    // ---- S^T = K Q^T (swapped operands; hi/lo split, 3 MFMAs each) ----
    // C layout: row = t = nt*16 + lg*4 + r, col = q = ln. Scores already
    // scaled (K carries SCK).
    f32x4 sacc[4];
#pragma unroll
    for (int nt = 0; nt < 4; ++nt) sacc[nt] = (f32x4){0.f, 0.f, 0.f, 0.f};
    __builtin_amdgcn_s_setprio(1);
#pragma unroll
    for (int c = 0; c < 2; ++c) {
      int d0 = c * 32 + lg * 8;
#pragma unroll
      for (int nt = 0; nt < 4; ++nt) {
        bf16x8 bhf =
            *reinterpret_cast<bf16x8*>(&KhiL[cur][swz(nt * 16 + ln, d0)]);
        bf16x8 blf =
            *reinterpret_cast<bf16x8*>(&KloL[cur][swz(nt * 16 + ln, d0)]);
        sacc[nt] = __builtin_amdgcn_mfma_f32_16x16x32_bf16(bhf, qhi[c], sacc[nt], 0, 0, 0);
        sacc[nt] = __builtin_amdgcn_mfma_f32_16x16x32_bf16(bhf, qlo[c], sacc[nt], 0, 0, 0);
        sacc[nt] = __builtin_amdgcn_mfma_f32_16x16x32_bf16(blf, qhi[c], sacc[nt], 0, 0, 0);
      }
    }
    __builtin_amdgcn_s_setprio(0);

    // ---- online softmax, per-thread (q = ln), defer-max (THR=8) ----
    float a0 = fmaxf(fmaxf(sacc[0][0], sacc[0][1]), fmaxf(sacc[0][2], sacc[0][3]));
    float a1 = fmaxf(fmaxf(sacc[1][0], sacc[1][1]), fmaxf(sacc[1][2], sacc[1][3]));
    float a2 = fmaxf(fmaxf(sacc[2][0], sacc[2][1]), fmaxf(sacc[2][2], sacc[2][3]));
    float a3 = fmaxf(fmaxf(sacc[3][0], sacc[3][1]), fmaxf(sacc[3][2], sacc[3][3]));
    float rm = fmaxf(fmaxf(a0, a1), fmaxf(a2, a3));
    rm = fmaxf(rm, __shfl_xor(rm, 16, 64));
    rm = fmaxf(rm, __shfl_xor(rm, 32, 64));
    if (!__all(rm <= mrun + 8.f)) {
      float mnew = fmaxf(mrun, rm);
      float sf = exp2f(mrun - mnew);
      mrun = mnew;
      float sfb[4];
#pragma unroll
      for (int r = 0; r < 4; ++r)
        sfb[r] = __shfl(sf, (l & 48) | (lg * 4 + r), 64);
      lrun *= sf;
#pragma unroll
      for (int nt = 0; nt < 4; ++nt)
#pragma unroll
        for (int r = 0; r < 4; ++r) oacc[nt][r] *= sfb[r];
    }
    const float ec = -mrun;
    float sv[4][4];
    float rs = 0.f;
#pragma unroll
    for (int nt = 0; nt < 4; ++nt)
#pragma unroll
      for (int r = 0; r < 4; ++r) {
        float p = exp2f(sacc[nt][r] + ec);
        sv[nt][r] = p;
        rs += p;
      }
    rs += __shfl_xor(rs, 16, 64);
    rs += __shfl_xor(rs, 32, 64);
    lrun += rs;

    // ---- P -> LDS (wave-private, hw packed cvt; lgkmcnt orders RAW) ----
#pragma unroll
    for (int nt = 0; nt < 4; ++nt) {
      uint2 pw;
      pw.x = cvt_pk_bf16(sv[nt][0], sv[nt][1]);
      pw.y = cvt_pk_bf16(sv[nt][2], sv[nt][3]);
      *reinterpret_cast<uint2*>(&Pl[w][swz(ln, nt * 16 + lg * 4)]) = pw;
    }

    // ---- O += P V ----
    __builtin_amdgcn_s_setprio(1);
#pragma unroll
    for (int c = 0; c < 2; ++c) {
      int tc = c * 32 + lg * 8;
      bf16x8 pa = *reinterpret_cast<bf16x8*>(&Pl[w][swz(ln, tc)]);
#pragma unroll
      for (int nt = 0; nt < 4; ++nt) {
        bf16x8 vb =
            *reinterpret_cast<bf16x8*>(&VTL[cur][swz(nt * 16 + ln, tc)]);
        oacc[nt] = __builtin_amdgcn_mfma_f32_16x16x32_bf16(pa, vb, oacc[nt], 0, 0, 0);
      }
    }
    __builtin_amdgcn_s_setprio(0);

    __builtin_amdgcn_s_barrier();  // all waves done reading buf[cur]
  };

  // unrolled x2: buffer index is a compile-time literal in each body
  for (int kt = 0; kt < NT; kt += 2) {
    tile(kt, 0);
    tile(kt + 1, 1);
  }

  // ---- epilogue: divide by row sum (broadcast lrun to acc rows), store ----
  float lr[4];
#pragma unroll
  for (int r = 0; r < 4; ++r)
    lr[r] = __shfl(lrun, (l & 48) | (lg * 4 + r), 64);
#pragma unroll
  for (int nt = 0; nt < 4; ++nt)
#pragma unroll
    for (int r = 0; r < 4; ++r) {
      obase[(size_t)(w * 16 + lg * 4 + r) * DD + nt * 16 + ln] =
          oacc[nt][r] / lr[r];
    }
}

// ---------------- fallback (round-4 kernel, raw inputs) if ws too small -----
__global__ __launch_bounds__(512) void attn_fwd_fb(
    const float* __restrict__ q, const float* __restrict__ k,
    const float* __restrict__ v, const int* __restrict__ mask,
    float* __restrict__ out) {
  __shared__ u16 Khi[KB * DD];
  __shared__ u16 Klo[KB * DD];
  __shared__ u16 VT[DD * KB];
  __shared__ u16 Pl[NW][16 * KB];

  const int tid = threadIdx.x;
  const int w = tid >> 6, l = tid & 63, lg = l >> 4, ln = l & 15;
  const int qt = blockIdx.x;
  const int bh = blockIdx.y;
  const int b = bh / HH;

  const float* qbase = q + ((size_t)bh * SLEN + (size_t)qt * QB) * DD;
  const float* kbase = k + (size_t)bh * DD * SLEN;
  const float* vbase = v + (size_t)bh * SLEN * DD;
  float* obase = out + ((size_t)bh * SLEN + (size_t)qt * QB) * DD;

  const int st_t = tid & 63;
  const int st_d0 = (tid >> 6) * 8;
  const int sv_d = tid & 63;
  const int sv_t0 = (tid >> 6) * 8;

  bf16x8 qhi[2], qlo[2];
  {
    const float* qrow = qbase + (size_t)(w * 16 + ln) * DD;
#pragma unroll
    for (int c = 0; c < 2; ++c) {
      int d0 = c * 32 + lg * 8;
#pragma unroll
      for (int j = 0; j < 8; ++j) {
        float x = qrow[d0 + j];
        u16 hi = f2bf_rne(x);
        qhi[c][j] = (short)hi;
        qlo[c][j] = (short)f2bf_rne(x - bf2f(hi));
      }
    }
  }
  const float addv =
      mask[b * SLEN + qt * QB + w * 16 + ln] ? 0.0f : -1e12f * LOG2E;
  const float SC = 0.125f * LOG2E;

  f32x4 oacc[4];
#pragma unroll
  for (int nt = 0; nt < 4; ++nt) oacc[nt] = (f32x4){0.f, 0.f, 0.f, 0.f};
  float mrun = -INFINITY, lrun = 0.f;

  for (int kt = 0; kt < NT; ++kt) {
    const int t0 = kt * KB;
    __syncthreads();
    bf16x8 khiv, klov, vv;
#pragma unroll
    for (int j = 0; j < 8; ++j) {
      float x = kbase[(size_t)(st_d0 + j) * SLEN + t0 + st_t];
      u16 hi = (u16)(__float_as_uint(x) >> 16);
      khiv[j] = (short)hi;
      klov[j] = (short)(u16)(__float_as_uint(x - bf2f(hi)) >> 16);
    }
#pragma unroll
    for (int j = 0; j < 8; ++j)
      vv[j] = (short)f2bf_rne(vbase[(size_t)(t0 + sv_t0 + j) * DD + sv_d]);
    *reinterpret_cast<bf16x8*>(&Khi[swz(st_t, st_d0)]) = khiv;
    *reinterpret_cast<bf16x8*>(&Klo[swz(st_t, st_d0)]) = klov;
    *reinterpret_cast<bf16x8*>(&VT[swz(sv_d, sv_t0)]) = vv;
    __syncthreads();

    f32x4 sacc[4];
#pragma unroll
    for (int nt = 0; nt < 4; ++nt) sacc[nt] = (f32x4){0.f, 0.f, 0.f, 0.f};
#pragma unroll
    for (int c = 0; c < 2; ++c) {
      int d0 = c * 32 + lg * 8;
#pragma unroll
      for (int nt = 0; nt < 4; ++nt) {
        bf16x8 bhf = *reinterpret_cast<bf16x8*>(&Khi[swz(nt * 16 + ln, d0)]);
        bf16x8 blf = *reinterpret_cast<bf16x8*>(&Klo[swz(nt * 16 + ln, d0)]);
        sacc[nt] = __builtin_amdgcn_mfma_f32_16x16x32_bf16(bhf, qhi[c], sacc[nt], 0, 0, 0);
        sacc[nt] = __builtin_amdgcn_mfma_f32_16x16x32_bf16(bhf, qlo[c], sacc[nt], 0, 0, 0);
        sacc[nt] = __builtin_amdgcn_mfma_f32_16x16x32_bf16(blf, qhi[c], sacc[nt], 0, 0, 0);
      }
    }
    float sv[4][4];
    float rm = -INFINITY;
#pragma unroll
    for (int nt = 0; nt < 4; ++nt)
#pragma unroll
      for (int r = 0; r < 4; ++r) {
        float x = sacc[nt][r] * SC + addv;
        sv[nt][r] = x;
        rm = fmaxf(rm, x);
      }
    rm = fmaxf(rm, __shfl_xor(rm, 16, 64));
    rm = fmaxf(rm, __shfl_xor(rm, 32, 64));
    float mnew = fmaxf(mrun, rm);
    float sf = exp2f(mrun - mnew);
    mrun = mnew;
    float rs = 0.f;
#pragma unroll
    for (int nt = 0; nt < 4; ++nt)
#pragma unroll
      for (int r = 0; r < 4; ++r) {
        float p = exp2f(sv[nt][r] - mnew);
        sv[nt][r] = p;
        rs += p;
      }
    rs += __shfl_xor(rs, 16, 64);
    rs += __shfl_xor(rs, 32, 64);
    lrun = lrun * sf + rs;
    float sfb[4];
#pragma unroll
    for (int r = 0; r < 4; ++r)
      sfb[r] = __shfl(sf, (l & 48) | (lg * 4 + r), 64);
#pragma unroll
    for (int nt = 0; nt < 4; ++nt)
#pragma unroll
      for (int r = 0; r < 4; ++r) oacc[nt][r] *= sfb[r];
#pragma unroll
    for (int nt = 0; nt < 4; ++nt) {
      uint2 pw;
      pw.x = cvt_pk_bf16(sv[nt][0], sv[nt][1]);
      pw.y = cvt_pk_bf16(sv[nt][2], sv[nt][3]);
      *reinterpret_cast<uint2*>(&Pl[w][swz(ln, nt * 16 + lg * 4)]) = pw;
    }
#pragma unroll
    for (int c = 0; c < 2; ++c) {
      int tc = c * 32 + lg * 8;
      bf16x8 pa = *reinterpret_cast<bf16x8*>(&Pl[w][swz(ln, tc)]);
#pragma unroll
      for (int nt = 0; nt < 4; ++nt) {
        bf16x8 vb = *reinterpret_cast<bf16x8*>(&VT[swz(nt * 16 + ln, tc)]);
        oacc[nt] = __builtin_amdgcn_mfma_f32_16x16x32_bf16(pa, vb, oacc[nt], 0, 0, 0);
      }
    }
  }
  float lr[4];
#pragma unroll
  for (int r = 0; r < 4; ++r)
    lr[r] = __shfl(lrun, (l & 48) | (lg * 4 + r), 64);
#pragma unroll
  for (int nt = 0; nt < 4; ++nt)
#pragma unroll
    for (int r = 0; r < 4; ++r) {
      obase[(size_t)(w * 16 + lg * 4 + r) * DD + nt * 16 + ln] =
          oacc[nt][r] / lr[r];
    }
}

extern "C" void kernel_launch(void* const* d_in, const int* in_sizes, int n_in,
                              void* d_out, int out_size, void* d_ws, size_t ws_size,
                              hipStream_t stream) {
  const float* q = (const float*)d_in[0];
  const float* k = (const float*)d_in[1];
  const float* v = (const float*)d_in[2];
  const int* mask = (const int*)d_in[3];
  float* out = (float*)d_out;

  const size_t nKV = (size_t)NBH * SLEN * DD;  // ushorts per array
  const size_t need = 3 * nKV * sizeof(u16);   // 25.2 MB
  if (ws_size >= need) {
    u16* wsKhi = (u16*)d_ws;
    u16* wsKlo = wsKhi + nKV;
    u16* wsVT = wsKlo + nKV;
    conv_kv<<<4096, 256, 0, stream>>>(k, v, wsKhi, wsKlo, wsVT);
    attn_fwd_pre<<<512, 512, 0, stream>>>(q, wsKhi, wsKlo, wsVT, mask, out);
  } else {
    attn_fwd_fb<<<dim3(SLEN / QB, NBH), 512, 0, stream>>>(q, k, v, mask, out);
  }
}